// Round 12
// baseline (405.602 us; speedup 1.0000x reference)
//
#include <hip/hip_runtime.h>
#include <hip/hip_bf16.h>
#include <stdint.h>

#define LN_EPS 1e-5f

typedef __hip_bfloat16 bf16;
typedef short short8 __attribute__((ext_vector_type(8)));
typedef float f32x4 __attribute__((ext_vector_type(4)));

static __device__ __forceinline__ float bf2f(short s) {
    unsigned int u = ((unsigned int)(unsigned short)s) << 16;
    return __uint_as_float(u);
}
static __device__ __forceinline__ short f2bf(float x) {
    __hip_bfloat16 h = __float2bfloat16(x);
    return *reinterpret_cast<short*>(&h);
}

// async global->LDS, 16B per lane; LDS dest = wave-uniform base + lane*16
static __device__ __forceinline__ void gload16(const void* g, void* l) {
    __builtin_amdgcn_global_load_lds((const __attribute__((address_space(1))) void*)g,
                                     (__attribute__((address_space(3))) void*)l, 16, 0, 0);
}

// ---------------- weight transpose + bf16 convert (+ optional per-k scale) ----------------
struct TDesc { const float* src; bf16* dst; int K; int N; int kOff; const float* scale; };
struct TDescs { TDesc d[9]; };

__global__ void transpose_all_kernel(TDescs descs) {
    TDesc t = descs.d[blockIdx.z];
    int kb = blockIdx.x * 32, nb = blockIdx.y * 32;
    if (kb >= t.K || nb >= t.N) return;
    __shared__ float tile[32][33];
    int tx = threadIdx.x & 31, ty = threadIdx.x >> 5;
    for (int i = ty; i < 32; i += 8) {
        int k = kb + i, n = nb + tx;
        float v = (k < t.K && n < t.N) ? t.src[(size_t)(t.kOff + k) * t.N + n] : 0.f;
        if (t.scale && k < t.K) v *= t.scale[k];
        tile[i][tx] = v;
    }
    __syncthreads();
    for (int i = ty; i < 32; i += 8) {
        int n = nb + i, k = kb + tx;
        if (n < t.N && k < t.K)
            t.dst[(size_t)n * t.K + k] = __float2bfloat16(tile[tx][i]);
    }
}

// u[n] = sum_k g[k]*W[1024+k][n], v[n] = sum_k beta[k]*W[1024+k][n]
__global__ void uv_kernel(const float* __restrict__ W, const float* __restrict__ g,
                          const float* __restrict__ be, float* __restrict__ u,
                          float* __restrict__ v) {
    int n = blockIdx.x * 256 + threadIdx.x;
    if (n >= 512) return;
    float su = 0.f, sv = 0.f;
    for (int k = 0; k < 512; k++) {
        float w = W[(size_t)(1024 + k) * 512 + n];
        su += g[k] * w;
        sv += be[k] * w;
    }
    u[n] = su;
    v[n] = sv;
}

// ---------------- f32 -> bf16 convert ----------------
__global__ void cvt_bf16_kernel(const float* __restrict__ src, bf16* __restrict__ dst, int n) {
    int i = blockIdx.x * 256 + threadIdx.x;
    int idx = i * 4;
    if (idx >= n) return;
    float4 v = *(const float4*)(src + idx);
    dst[idx + 0] = __float2bfloat16(v.x);
    dst[idx + 1] = __float2bfloat16(v.y);
    dst[idx + 2] = __float2bfloat16(v.z);
    dst[idx + 3] = __float2bfloat16(v.w);
}

// ---------------- stats finalize: stats[r] = {mu, rs} from 8 partials (4 blk x 2 wn) ----------------
__global__ void stats_finalize_kernel(const float2* __restrict__ partials,
                                      float2* __restrict__ stats, int R) {
    int r = blockIdx.x * 256 + threadIdx.x;
    if (r >= R) return;
    float s = 0.f, q = 0.f;
#pragma unroll
    for (int i = 0; i < 8; i++) {
        float2 pp = partials[(size_t)r * 8 + i];
        s += pp.x; q += pp.y;
    }
    float mu = s * (1.f / 512.f);
    float var = q * (1.f / 512.f) - mu * mu;
    stats[r] = make_float2(mu, rsqrtf(var + LN_EPS));
}

// ============ T2 fused: C = relu(attr@w1+b1) @ BT^T + b2, with stats partials ============
// BM=256, BN=128, BK=64, 512 thr / 8 waves. A-tile (H1) computed ON THE FLY from
// attr (4-wide) + w1 slice and ds_written into swizzled LDS; B staged via gload16.
__global__ __launch_bounds__(512, 4) void t2_fused_kernel(
    const float* __restrict__ attr, const float* __restrict__ w1,
    const float* __restrict__ b1, const bf16* __restrict__ BT,
    const float* __restrict__ bias, bf16* __restrict__ C,
    float2* __restrict__ partials, int M, int N, int K) {
    __shared__ short SMEM[384 * 64];   // 48 KB: rows 0-255 H1, 256-383 B
    const int t = threadIdx.x;
    const int lane = t & 63, w = t >> 6;
    const int wm = w >> 1, wn = w & 1;
    const int lr = lane & 15, lh = lane >> 4;

    // m204 bijective XCD swizzle
    int gx = gridDim.x;
    int nwg = gx * gridDim.y;
    int orig = blockIdx.y * gx + blockIdx.x;
    int q = nwg >> 3, r = nwg & 7;
    int xcd = orig & 7, loc = orig >> 3;
    int wg = (xcd < r ? xcd * (q + 1) : r * (q + 1) + (xcd - r) * q) + loc;
    int bx = wg % gx, by = wg / gx;
    const int row0 = by * 256;
    const int col0 = bx * 128;

    // H1 on-the-fly mapping: colgrp = t&7 (8 cols), rowblk = t>>3 (4 rows)
    const int cg = t & 7;
    const int rowblk = t >> 3;
    float av[4][4];
#pragma unroll
    for (int rr = 0; rr < 4; rr++) {
        int e = row0 + rowblk * 4 + rr; if (e >= M) e = M - 1;
        float4 a = *(const float4*)(attr + (size_t)e * 4);
        av[rr][0] = a.x; av[rr][1] = a.y; av[rr][2] = a.z; av[rr][3] = a.w;
    }

    // B staging: wave w stages B rows [w*16, w*16+16)
    const int sr3 = lane >> 3;
    const int su = (lane & 7) ^ sr3;
    const int scol = su * 8;
    const bf16* gbP[2];
#pragma unroll
    for (int c = 0; c < 2; c++) {
        int rb = col0 + w * 16 + c * 8 + sr3; if (rb >= N) rb = N - 1;
        gbP[c] = BT + (size_t)rb * K + scol;
    }

    f32x4 acc[4][4];
#pragma unroll
    for (int i = 0; i < 4; i++)
#pragma unroll
        for (int j = 0; j < 4; j++) acc[i][j] = {0.f, 0.f, 0.f, 0.f};

    for (int k0 = 0; k0 < K; k0 += 64) {
        // B async stage
#pragma unroll
        for (int c = 0; c < 2; c++)
            gload16(gbP[c] + k0, SMEM + (256 + w * 16 + c * 8) * 64);
        // H1 compute + swizzled ds_write
        int kc = k0 + cg * 8;
        float4 bb0 = *(const float4*)(b1 + kc);
        float4 bb1 = *(const float4*)(b1 + kc + 4);
        float wv[4][8];
#pragma unroll
        for (int j2 = 0; j2 < 4; j2++) {
            float4 w0 = *(const float4*)(w1 + j2 * 512 + kc);
            float4 w1v = *(const float4*)(w1 + j2 * 512 + kc + 4);
            wv[j2][0] = w0.x; wv[j2][1] = w0.y; wv[j2][2] = w0.z; wv[j2][3] = w0.w;
            wv[j2][4] = w1v.x; wv[j2][5] = w1v.y; wv[j2][6] = w1v.z; wv[j2][7] = w1v.w;
        }
#pragma unroll
        for (int rr = 0; rr < 4; rr++) {
            int row = rowblk * 4 + rr;
            float c8[8] = {bb0.x, bb0.y, bb0.z, bb0.w, bb1.x, bb1.y, bb1.z, bb1.w};
#pragma unroll
            for (int j2 = 0; j2 < 4; j2++)
#pragma unroll
                for (int j = 0; j < 8; j++) c8[j] += av[rr][j2] * wv[j2][j];
            short8 h;
#pragma unroll
            for (int j = 0; j < 8; j++) h[j] = f2bf(fmaxf(c8[j], 0.f));
            *(short8*)&SMEM[row * 64 + ((cg ^ (row & 7)) * 8)] = h;
        }
        __syncthreads();
#pragma unroll
        for (int kk = 0; kk < 64; kk += 32) {
            short8 af[4], bfv[4];
#pragma unroll
            for (int mf = 0; mf < 4; mf++) {
                int rowa = wm * 64 + mf * 16 + lr;
                int ua = ((kk >> 3) + lh) ^ (rowa & 7);
                af[mf] = *(const short8*)&SMEM[rowa * 64 + ua * 8];
            }
#pragma unroll
            for (int nf = 0; nf < 4; nf++) {
                int rowb = 256 + wn * 64 + nf * 16 + lr;
                int ub = ((kk >> 3) + lh) ^ (rowb & 7);
                bfv[nf] = *(const short8*)&SMEM[rowb * 64 + ub * 8];
            }
#pragma unroll
            for (int mf = 0; mf < 4; mf++)
#pragma unroll
                for (int nf = 0; nf < 4; nf++)
                    acc[mf][nf] = __builtin_amdgcn_mfma_f32_16x16x32_bf16(
                        af[mf], bfv[nf], acc[mf][nf], 0, 0, 0);
        }
        __syncthreads();
    }

    // epilogue: +bias, store, per-row stats partials (slot = bx*2 + wn)
    short* Cw = SMEM + w * (32 * 66);
    const int rgrp = lane >> 3, u = lane & 7;
#pragma unroll
    for (int hp = 0; hp < 2; hp++) {
#pragma unroll
        for (int mf2 = 0; mf2 < 2; mf2++) {
            int mf = hp * 2 + mf2;
#pragma unroll
            for (int nf = 0; nf < 4; nf++)
#pragma unroll
                for (int r2 = 0; r2 < 4; r2++) {
                    int rl = mf2 * 16 + lh * 4 + r2;
                    Cw[rl * 66 + nf * 16 + lr] = f2bf(acc[mf][nf][r2]);
                }
        }
#pragma unroll
        for (int rr = 0; rr < 4; rr++) {
            int rl = rr * 8 + rgrp;
            int grow = row0 + wm * 64 + hp * 32 + rl;
            int gcol = col0 + wn * 64 + u * 8;
            short8 vv = *(const short8*)&Cw[rl * 66 + u * 8];
            float vf[8];
#pragma unroll
            for (int j = 0; j < 8; j++) vf[j] = bf2f(vv[j]);
            float4 c0 = *(const float4*)(bias + gcol);
            float4 c1 = *(const float4*)(bias + gcol + 4);
            float bb[8] = {c0.x, c0.y, c0.z, c0.w, c1.x, c1.y, c1.z, c1.w};
#pragma unroll
            for (int j = 0; j < 8; j++) vf[j] += bb[j];
            float s1 = 0.f, s2 = 0.f;
#pragma unroll
            for (int j = 0; j < 8; j++) { s1 += vf[j]; s2 += vf[j] * vf[j]; }
            s1 += __shfl_xor(s1, 1, 64); s2 += __shfl_xor(s2, 1, 64);
            s1 += __shfl_xor(s1, 2, 64); s2 += __shfl_xor(s2, 2, 64);
            s1 += __shfl_xor(s1, 4, 64); s2 += __shfl_xor(s2, 4, 64);
            if (u == 0 && grow < M)
                partials[(size_t)grow * 8 + bx * 2 + wn] = make_float2(s1, s2);
            short8 o;
#pragma unroll
            for (int j = 0; j < 8; j++) o[j] = f2bf(vf[j]);
            if (grow < M && gcol < N)
                *(short8*)(C + (size_t)grow * N + gcol) = o;
        }
    }
}

// ============ gemm256: BM=256, BN=128, BK=64, 512 thr / 8 waves ============
// EPI: 1 +bias | 4 LN-fold + gather + relu.  STATS: write per-row {sum,sumsq} partials.
template <int EPI, int STATS>
__global__ __launch_bounds__(512, 4) void gemm256_kernel(
    const bf16* __restrict__ A, const bf16* __restrict__ BT,
    const float* __restrict__ bias, bf16* __restrict__ C, int M, int N, int K,
    const bf16* __restrict__ gridp, const bf16* __restrict__ meshp,
    const int* __restrict__ send, const int* __restrict__ recv,
    const float2* __restrict__ stats, const float* __restrict__ uvec,
    const float* __restrict__ vvec, float2* __restrict__ partials) {
    __shared__ short SMEM[384 * 64];   // 48 KB
    const int t = threadIdx.x;
    const int lane = t & 63, w = t >> 6;
    const int wm = w >> 1, wn = w & 1;
    const int lr = lane & 15, lh = lane >> 4;

    int gx = gridDim.x;
    int nwg = gx * gridDim.y;
    int orig = blockIdx.y * gx + blockIdx.x;
    int q = nwg >> 3, r = nwg & 7;
    int xcd = orig & 7, loc = orig >> 3;
    int wg = (xcd < r ? xcd * (q + 1) : r * (q + 1) + (xcd - r) * q) + loc;
    int bx = wg % gx, by = wg / gx;
    const int row0 = by * 256;
    const int col0 = bx * 128;

    const int sr3 = lane >> 3;
    const int su = (lane & 7) ^ sr3;
    const int scol = su * 8;
    const bf16* gp6[6];
#pragma unroll
    for (int i = 0; i < 6; i++) {
        int rr = w * 48 + i * 8 + sr3;
        if (rr < 256) {
            int ra = row0 + rr; if (ra >= M) ra = M - 1;
            gp6[i] = A + (size_t)ra * K + scol;
        } else {
            int rb = col0 + (rr - 256); if (rb >= N) rb = N - 1;
            gp6[i] = BT + (size_t)rb * K + scol;
        }
    }

    f32x4 acc[4][4];
#pragma unroll
    for (int i = 0; i < 4; i++)
#pragma unroll
        for (int j = 0; j < 4; j++) acc[i][j] = {0.f, 0.f, 0.f, 0.f};

    for (int k0 = 0; k0 < K; k0 += 64) {
#pragma unroll
        for (int i = 0; i < 6; i++)
            gload16(gp6[i] + k0, SMEM + (w * 48 + i * 8) * 64);
        __syncthreads();
#pragma unroll
        for (int kk = 0; kk < 64; kk += 32) {
            short8 af[4], bfv[4];
#pragma unroll
            for (int mf = 0; mf < 4; mf++) {
                int rowa = wm * 64 + mf * 16 + lr;
                int ua = ((kk >> 3) + lh) ^ (rowa & 7);
                af[mf] = *(const short8*)&SMEM[rowa * 64 + ua * 8];
            }
#pragma unroll
            for (int nf = 0; nf < 4; nf++) {
                int rowb = 256 + wn * 64 + nf * 16 + lr;
                int ub = ((kk >> 3) + lh) ^ (rowb & 7);
                bfv[nf] = *(const short8*)&SMEM[rowb * 64 + ub * 8];
            }
#pragma unroll
            for (int mf = 0; mf < 4; mf++)
#pragma unroll
                for (int nf = 0; nf < 4; nf++)
                    acc[mf][nf] = __builtin_amdgcn_mfma_f32_16x16x32_bf16(
                        af[mf], bfv[nf], acc[mf][nf], 0, 0, 0);
        }
        __syncthreads();
    }

    short* Cw = SMEM + w * (32 * 66);
    const int rgrp = lane >> 3, u = lane & 7;
#pragma unroll
    for (int hp = 0; hp < 2; hp++) {
#pragma unroll
        for (int mf2 = 0; mf2 < 2; mf2++) {
            int mf = hp * 2 + mf2;
#pragma unroll
            for (int nf = 0; nf < 4; nf++)
#pragma unroll
                for (int r2 = 0; r2 < 4; r2++) {
                    int rl = mf2 * 16 + lh * 4 + r2;
                    Cw[rl * 66 + nf * 16 + lr] = f2bf(acc[mf][nf][r2]);
                }
        }
#pragma unroll
        for (int rr = 0; rr < 4; rr++) {
            int rl = rr * 8 + rgrp;
            int grow = row0 + wm * 64 + hp * 32 + rl;
            int gcol = col0 + wn * 64 + u * 8;
            short8 vv = *(const short8*)&Cw[rl * 66 + u * 8];
            float vf[8];
#pragma unroll
            for (int j = 0; j < 8; j++) vf[j] = bf2f(vv[j]);
            if (EPI == 4) {
                int e = grow < M ? grow : M - 1;
                float2 st = stats[e];
                float rs = st.y, mrs = st.x * st.y;
                float4 u0 = *(const float4*)(uvec + gcol), u1 = *(const float4*)(uvec + gcol + 4);
                float4 v0 = *(const float4*)(vvec + gcol), v1 = *(const float4*)(vvec + gcol + 4);
                float uu[8] = {u0.x, u0.y, u0.z, u0.w, u1.x, u1.y, u1.z, u1.w};
                float vvv[8] = {v0.x, v0.y, v0.z, v0.w, v1.x, v1.y, v1.z, v1.w};
#pragma unroll
                for (int j = 0; j < 8; j++) vf[j] = rs * vf[j] - mrs * uu[j] + vvv[j];
            }
            {
                float4 c0 = *(const float4*)(bias + gcol);
                float4 c1 = *(const float4*)(bias + gcol + 4);
                float bb[8] = {c0.x, c0.y, c0.z, c0.w, c1.x, c1.y, c1.z, c1.w};
#pragma unroll
                for (int j = 0; j < 8; j++) vf[j] += bb[j];
            }
            if (EPI == 4) {
                int e = grow < M ? grow : M - 1;
                int rn = recv[e], sn = send[e];
                short8 gp = *(const short8*)(gridp + (size_t)rn * 512 + gcol);
                short8 mp = *(const short8*)(meshp + (size_t)sn * 512 + gcol);
#pragma unroll
                for (int j = 0; j < 8; j++) vf[j] += bf2f(gp[j]) + bf2f(mp[j]);
#pragma unroll
                for (int j = 0; j < 8; j++) vf[j] = fmaxf(vf[j], 0.f);
            }
            if (STATS) {
                float s1 = 0.f, s2 = 0.f;
#pragma unroll
                for (int j = 0; j < 8; j++) { s1 += vf[j]; s2 += vf[j] * vf[j]; }
                s1 += __shfl_xor(s1, 1, 64); s2 += __shfl_xor(s2, 1, 64);
                s1 += __shfl_xor(s1, 2, 64); s2 += __shfl_xor(s2, 2, 64);
                s1 += __shfl_xor(s1, 4, 64); s2 += __shfl_xor(s2, 4, 64);
                if (u == 0 && grow < M)
                    partials[(size_t)grow * 8 + bx * 2 + wn] = make_float2(s1, s2);
            }
            short8 o;
#pragma unroll
            for (int j = 0; j < 8; j++) o[j] = f2bf(vf[j]);
            if (grow < M && gcol < N)
                *(short8*)(C + (size_t)grow * N + gcol) = o;
        }
    }
}

// ============ gemm_bt: 128x128, R5 single-buffer loop ============
// EPI: 0 none | 1 +bias | 2 +bias+relu | 5 final-LN (N==128, f32 out)
template <int EPI>
__global__ __launch_bounds__(256, 4) void gemm_bt_kernel(
    const bf16* __restrict__ A, const bf16* __restrict__ BT,
    const float* __restrict__ bias, bf16* __restrict__ C, int M, int N, int K,
    const float* __restrict__ fg, const float* __restrict__ fb,
    float* __restrict__ OutF) {
    __shared__ short SMEM[132 * 128 + 64];
    const int t = threadIdx.x;
    const int lane = t & 63, w = t >> 6;
    const int wm = w >> 1, wn = w & 1;
    const int lr = lane & 15, lh = lane >> 4;

    int gx = gridDim.x;
    int nwg = gx * gridDim.y;
    int orig = blockIdx.y * gx + blockIdx.x;
    int q = nwg >> 3, r = nwg & 7;
    int xcd = orig & 7, loc = orig >> 3;
    int wg = (xcd < r ? xcd * (q + 1) : r * (q + 1) + (xcd - r) * q) + loc;
    int bx = wg % gx, by = wg / gx;
    const int row0 = by * 128;
    const int col0 = bx * 128;

    const int sr3 = lane >> 3;
    const int su = (lane & 7) ^ sr3;
    const int srow = w * 32 + sr3;
    const int scol = su * 8;
    const bf16* gaP[4];
    const bf16* gbP[4];
#pragma unroll
    for (int i = 0; i < 4; i++) {
        int ra = row0 + srow + i * 8; if (ra >= M) ra = M - 1;
        int rb = col0 + srow + i * 8; if (rb >= N) rb = N - 1;
        gaP[i] = A + (size_t)ra * K + scol;
        gbP[i] = BT + (size_t)rb * K + scol;
    }

    f32x4 acc[4][4];
#pragma unroll
    for (int i = 0; i < 4; i++)
#pragma unroll
        for (int j = 0; j < 4; j++) acc[i][j] = {0.f, 0.f, 0.f, 0.f};

    for (int k0 = 0; k0 < K; k0 += 64) {
        short* la = SMEM + w * 32 * 64;
        short* lb = la + 8192;
#pragma unroll
        for (int i = 0; i < 4; i++) {
            gload16(gaP[i] + k0, la + i * 8 * 64);
            gload16(gbP[i] + k0, lb + i * 8 * 64);
        }
        __syncthreads();
#pragma unroll
        for (int kk = 0; kk < 64; kk += 32) {
            short8 af[4], bfv[4];
#pragma unroll
            for (int mf = 0; mf < 4; mf++) {
                int rowa = wm * 64 + mf * 16 + lr;
                int ua = ((kk >> 3) + lh) ^ (rowa & 7);
                af[mf] = *(const short8*)&SMEM[rowa * 64 + ua * 8];
            }
#pragma unroll
            for (int nf = 0; nf < 4; nf++) {
                int rowb = wn * 64 + nf * 16 + lr;
                int ub = ((kk >> 3) + lh) ^ (rowb & 7);
                bfv[nf] = *(const short8*)&SMEM[8192 + rowb * 64 + ub * 8];
            }
#pragma unroll
            for (int mf = 0; mf < 4; mf++)
#pragma unroll
                for (int nf = 0; nf < 4; nf++)
                    acc[mf][nf] = __builtin_amdgcn_mfma_f32_16x16x32_bf16(
                        af[mf], bfv[nf], acc[mf][nf], 0, 0, 0);
        }
        __syncthreads();
    }

    if (EPI == 5) {
        short* Cs = SMEM;   // [128][132]
#pragma unroll
        for (int nf = 0; nf < 4; nf++) {
            float bv = bias[wn * 64 + nf * 16 + lr];
#pragma unroll
            for (int mf = 0; mf < 4; mf++)
#pragma unroll
                for (int r2 = 0; r2 < 4; r2++) {
                    int rl = wm * 64 + mf * 16 + lh * 4 + r2;
                    Cs[rl * 132 + wn * 64 + nf * 16 + lr] = f2bf(acc[mf][nf][r2] + bv);
                }
        }
        __syncthreads();
        int rl = w * 32 + (lane >> 1);
        int half = lane & 1;
        short8 vs[8];
        float s = 0.f, s2 = 0.f;
#pragma unroll
        for (int j8 = 0; j8 < 8; j8++) {
            vs[j8] = *(const short8*)&Cs[rl * 132 + half * 64 + j8 * 8];
#pragma unroll
            for (int j = 0; j < 8; j++) {
                float f = bf2f(vs[j8][j]);
                s += f; s2 += f * f;
            }
        }
        s += __shfl_xor(s, 1, 64);
        s2 += __shfl_xor(s2, 1, 64);
        float mu = s * (1.f / 128.f);
        float var = s2 * (1.f / 128.f) - mu * mu;
        float rs = rsqrtf(var + LN_EPS);
        int grow = row0 + rl;
#pragma unroll
        for (int j8 = 0; j8 < 8; j8++) {
            int c0 = half * 64 + j8 * 8;
            float4 g0 = *(const float4*)(fg + c0), g1 = *(const float4*)(fg + c0 + 4);
            float4 b0 = *(const float4*)(fb + c0), b1v = *(const float4*)(fb + c0 + 4);
            float gg[8] = {g0.x, g0.y, g0.z, g0.w, g1.x, g1.y, g1.z, g1.w};
            float bb[8] = {b0.x, b0.y, b0.z, b0.w, b1v.x, b1v.y, b1v.z, b1v.w};
            float4 o0, o1;
#pragma unroll
            for (int j = 0; j < 8; j++) {
                float y = (bf2f(vs[j8][j]) - mu) * rs * gg[j] + bb[j];
                if (j < 4) ((float*)&o0)[j] = y; else ((float*)&o1)[j - 4] = y;
            }
            *(float4*)(OutF + (size_t)grow * 128 + c0) = o0;
            *(float4*)(OutF + (size_t)grow * 128 + c0 + 4) = o1;
        }
        return;
    }

    short* Cw = SMEM + w * (32 * 66);
    const int rgrp = lane >> 3, u = lane & 7;
#pragma unroll
    for (int hp = 0; hp < 2; hp++) {
#pragma unroll
        for (int mf2 = 0; mf2 < 2; mf2++) {
            int mf = hp * 2 + mf2;
#pragma unroll
            for (int nf = 0; nf < 4; nf++)
#pragma unroll
                for (int r2 = 0; r2 < 4; r2++) {
                    int rl = mf2 * 16 + lh * 4 + r2;
                    Cw[rl * 66 + nf * 16 + lr] = f2bf(acc[mf][nf][r2]);
                }
        }
#pragma unroll
        for (int rr = 0; rr < 4; rr++) {
            int rl = rr * 8 + rgrp;
            int grow = row0 + wm * 64 + hp * 32 + rl;
            int gcol = col0 + wn * 64 + u * 8;
            short8 vv = *(const short8*)&Cw[rl * 66 + u * 8];
            float vf[8];
#pragma unroll
            for (int j = 0; j < 8; j++) vf[j] = bf2f(vv[j]);
            if (EPI >= 1) {
                float4 c0 = *(const float4*)(bias + gcol);
                float4 c1 = *(const float4*)(bias + gcol + 4);
                float bb[8] = {c0.x, c0.y, c0.z, c0.w, c1.x, c1.y, c1.z, c1.w};
#pragma unroll
                for (int j = 0; j < 8; j++) vf[j] += bb[j];
            }
            if (EPI == 2) {
#pragma unroll
                for (int j = 0; j < 8; j++) vf[j] = fmaxf(vf[j], 0.f);
            }
            short8 o;
#pragma unroll
            for (int j = 0; j < 8; j++) o[j] = f2bf(vf[j]);
            if (grow < M && gcol < N)
                *(short8*)(C + (size_t)grow * N + gcol) = o;
        }
    }
}

// ---------------- LayerNorm with residual add (DN=512) ----------------
__global__ void ln_resid_kernel(const bf16* __restrict__ X, const float* __restrict__ gw,
                                const float* __restrict__ bw, bf16* __restrict__ outb,
                                const bf16* __restrict__ resid, int R) {
    int row = blockIdx.x * 4 + (threadIdx.x >> 6);
    if (row >= R) return;
    int lane = threadIdx.x & 63;
    short8 t8 = *(const short8*)(X + (size_t)row * 512 + lane * 8);
    float v[8];
#pragma unroll
    for (int j = 0; j < 8; j++) v[j] = bf2f(t8[j]);
    float s = 0.f, s2 = 0.f;
#pragma unroll
    for (int j = 0; j < 8; j++) { s += v[j]; s2 += v[j] * v[j]; }
#pragma unroll
    for (int o = 32; o > 0; o >>= 1) {
        s += __shfl_xor(s, o, 64);
        s2 += __shfl_xor(s2, o, 64);
    }
    float mu = s * (1.f / 512.f);
    float var = s2 * (1.f / 512.f) - mu * mu;
    float rs = rsqrtf(var + LN_EPS);
    int d0 = lane * 8;
    short8 rv = *(const short8*)(resid + (size_t)row * 512 + d0);
    short8 o;
#pragma unroll
    for (int j = 0; j < 8; j++) {
        float y = (v[j] - mu) * rs * gw[d0 + j] + bw[d0 + j];
        o[j] = f2bf(bf2f(rv[j]) + y);
    }
    *(short8*)(outb + (size_t)row * 512 + d0) = o;
}

// ---------------- CSR build ----------------
__global__ void degree_kernel(const int* __restrict__ recv, int* __restrict__ deg, int E) {
    int e = blockIdx.x * 256 + threadIdx.x;
    if (e < E) atomicAdd(&deg[recv[e]], 1);
}

__global__ void scan_kernel(const int* __restrict__ deg, int* __restrict__ off) {
    __shared__ int partial[1024];
    int t = threadIdx.x;
    int base = t * 16;
    int v[16];
    int s = 0;
#pragma unroll
    for (int i = 0; i < 16; i++) { v[i] = deg[base + i]; s += v[i]; }
    partial[t] = s;
    __syncthreads();
    for (int o = 1; o < 1024; o <<= 1) {
        int x = (t >= o) ? partial[t - o] : 0;
        __syncthreads();
        partial[t] += x;
        __syncthreads();
    }
    int run = (t == 0) ? 0 : partial[t - 1];
#pragma unroll
    for (int i = 0; i < 16; i++) { off[base + i] = run; run += v[i]; }
    if (t == 1023) off[16384] = run;
}

__global__ void scatter_kernel(const int* __restrict__ recv, const int* __restrict__ off,
                               int* __restrict__ cnt, int* __restrict__ edges, int E) {
    int e = blockIdx.x * 256 + threadIdx.x;
    if (e < E) {
        int r = recv[e];
        int p = atomicAdd(&cnt[r], 1);
        edges[off[r] + p] = e;
    }
}

// ---------------- aggregate LN(msg) by receiver + build X2 = cat(grid_bf, aggr) ----------------
__global__ void aggregate_kernel(const bf16* __restrict__ T5, const float2* __restrict__ stats,
                                 const float* __restrict__ gw, const float* __restrict__ bw,
                                 const bf16* __restrict__ gridb,
                                 const int* __restrict__ off, const int* __restrict__ edges,
                                 bf16* __restrict__ X2, int G) {
    int g = blockIdx.x * 4 + (threadIdx.x >> 6);
    if (g >= G) return;
    int lane = threadIdx.x & 63;
    int d0 = lane * 8;
    float gg[8], bb[8];
    {
        float4 a = *(const float4*)(gw + d0), b = *(const float4*)(gw + d0 + 4);
        gg[0]=a.x; gg[1]=a.y; gg[2]=a.z; gg[3]=a.w; gg[4]=b.x; gg[5]=b.y; gg[6]=b.z; gg[7]=b.w;
        float4 c = *(const float4*)(bw + d0), d = *(const float4*)(bw + d0 + 4);
        bb[0]=c.x; bb[1]=c.y; bb[2]=c.z; bb[3]=c.w; bb[4]=d.x; bb[5]=d.y; bb[6]=d.z; bb[7]=d.w;
    }
    float s[8] = {0.f, 0.f, 0.f, 0.f, 0.f, 0.f, 0.f, 0.f};
    int a = off[g], b = off[g + 1];
    for (int i = a; i < b; i++) {
        int e = edges[i];
        float2 st = stats[e];
        short8 m = *(const short8*)(T5 + (size_t)e * 512 + d0);
#pragma unroll
        for (int j = 0; j < 8; j++)
            s[j] += (bf2f(m[j]) - st.x) * st.y * gg[j] + bb[j];
    }
    *(short8*)(X2 + (size_t)g * 1024 + d0) = *(const short8*)(gridb + (size_t)g * 512 + d0);
    short8 o;
#pragma unroll
    for (int j = 0; j < 8; j++) o[j] = f2bf(s[j]);
    *(short8*)(X2 + (size_t)g * 1024 + 512 + d0) = o;
}

extern "C" void kernel_launch(void* const* d_in, const int* in_sizes, int n_in,
                              void* d_out, int out_size, void* d_ws, size_t ws_size,
                              hipStream_t stream) {
    const int NM = 2562, NG = 16384, NE = 49152;
    const float* mesh   = (const float*)d_in[0];
    const float* grid   = (const float*)d_in[1];
    const float* attr   = (const float*)d_in[2];
    const int*   eidx   = (const int*)d_in[3];
    const int*   send   = eidx;
    const int*   recv   = eidx + NE;
    const float* emlp_w1 = (const float*)d_in[4];
    const float* emlp_b1 = (const float*)d_in[5];
    const float* emlp_w2 = (const float*)d_in[6];
    const float* emlp_b2 = (const float*)d_in[7];
    const float* emlp_g  = (const float*)d_in[8];
    const float* emlp_be = (const float*)d_in[9];
    const float* ge_w1 = (const float*)d_in[10];
    const float* ge_b1 = (const float*)d_in[11];
    const float* ge_w2 = (const float*)d_in[12];
    const float* ge_b2 = (const float*)d_in[13];
    const float* ge_g  = (const float*)d_in[14];
    const float* ge_be = (const float*)d_in[15];
    const float* gn_w1 = (const float*)d_in[16];
    const float* gn_b1 = (const float*)d_in[17];
    const float* gn_w2 = (const float*)d_in[18];
    const float* gn_b2 = (const float*)d_in[19];
    const float* gn_g  = (const float*)d_in[20];
    const float* gn_be = (const float*)d_in[21];
    const float* fin_w1 = (const float*)d_in[22];
    const float* fin_b1 = (const float*)d_in[23];
    const float* fin_w2 = (const float*)d_in[24];
    const float* fin_b2 = (const float*)d_in[25];
    const float* fin_g  = (const float*)d_in[26];
    const float* fin_be = (const float*)d_in[27];

    char* p = (char*)d_ws;
    auto take = [&](size_t bytes) -> char* {
        char* r = p;
        p += (bytes + 255) & ~(size_t)255;
        return r;
    };
    bf16* emlp_w2T = (bf16*)take((size_t)512 * 512 * 2);
    bf16* geA_T    = (bf16*)take((size_t)512 * 512 * 2);
    bf16* geB_T    = (bf16*)take((size_t)512 * 512 * 2);
    bf16* geC_T    = (bf16*)take((size_t)512 * 512 * 2);   // pre-scaled by emlp_g
    bf16* ge_w2T   = (bf16*)take((size_t)512 * 512 * 2);
    bf16* gn_w1T   = (bf16*)take((size_t)512 * 1024 * 2);
    bf16* gn_w2T   = (bf16*)take((size_t)512 * 512 * 2);
    bf16* fin_w1T  = (bf16*)take((size_t)512 * 512 * 2);
    bf16* fin_w2T  = (bf16*)take((size_t)128 * 512 * 2);
    bf16* grid_bf  = (bf16*)take((size_t)NG * 512 * 2);
    bf16* mesh_bf  = (bf16*)take((size_t)NM * 512 * 2);
    bf16* bufA     = (bf16*)take((size_t)NE * 512 * 2);
    bf16* bufB     = (bf16*)take((size_t)NE * 512 * 2);
    bf16* bufC     = (bf16*)take((size_t)NG * 512 * 2);
    bf16* bufD     = (bf16*)take((size_t)NM * 512 * 2);
    float2* stats  = (float2*)take((size_t)NE * 8);
    float2* parts  = (float2*)take((size_t)NE * 8 * 8);
    float* uvecW   = (float*)take((size_t)512 * 4);
    float* vvecW   = (float*)take((size_t)512 * 4);
    int*  deg      = (int*)take((size_t)NG * 4);
    int*  cnt      = (int*)take((size_t)NG * 4);
    int*  csr_off  = (int*)take((size_t)(NG + 1) * 4);
    int*  csr_edge = (int*)take((size_t)NE * 4);

    const bf16* nbf = nullptr; const int* ni = nullptr;
    const float2* nst = nullptr; const float* nf = nullptr;
    float2* nfp = nullptr;

    // 1) transpose + bf16-convert all GEMM weights (geC pre-scaled by emlp_g)
    TDescs td;
    td.d[0] = {emlp_w2, emlp_w2T, 512, 512, 0, nullptr};
    td.d[1] = {ge_w1,   geA_T,    512, 512, 0, nullptr};
    td.d[2] = {ge_w1,   geB_T,    512, 512, 512, nullptr};
    td.d[3] = {ge_w1,   geC_T,    512, 512, 1024, emlp_g};
    td.d[4] = {ge_w2,   ge_w2T,   512, 512, 0, nullptr};
    td.d[5] = {gn_w1,   gn_w1T,  1024, 512, 0, nullptr};
    td.d[6] = {gn_w2,   gn_w2T,   512, 512, 0, nullptr};
    td.d[7] = {fin_w1,  fin_w1T,  512, 512, 0, nullptr};
    td.d[8] = {fin_w2,  fin_w2T,  512, 128, 0, nullptr};
    hipLaunchKernelGGL(transpose_all_kernel, dim3(32, 16, 9), dim3(256), 0, stream, td);
    hipLaunchKernelGGL(uv_kernel, dim3(2), dim3(256), 0, stream,
                       ge_w1, emlp_g, emlp_be, uvecW, vvecW);

    // 2) bf16 inputs + CSR build
    hipLaunchKernelGGL(cvt_bf16_kernel, dim3((NG * 512 / 4 + 255) / 256), dim3(256), 0, stream,
                       grid, grid_bf, NG * 512);
    hipLaunchKernelGGL(cvt_bf16_kernel, dim3((NM * 512 / 4 + 255) / 256), dim3(256), 0, stream,
                       mesh, mesh_bf, NM * 512);
    hipMemsetAsync(deg, 0, (size_t)NG * 4, stream);
    hipMemsetAsync(cnt, 0, (size_t)NG * 4, stream);
    hipLaunchKernelGGL(degree_kernel, dim3((NE + 255) / 256), dim3(256), 0, stream, recv, deg, NE);
    hipLaunchKernelGGL(scan_kernel, dim3(1), dim3(1024), 0, stream, deg, csr_off);
    hipLaunchKernelGGL(scatter_kernel, dim3((NE + 255) / 256), dim3(256), 0, stream,
                       recv, csr_off, cnt, csr_edge, NE);

    // 3) T2 = relu(attr@emlp_w1+b1) @ emlp_w2 + b2 -> bufB, with stats partials
    hipLaunchKernelGGL(t2_fused_kernel, dim3(4, NE / 256), dim3(512), 0, stream,
                       attr, emlp_w1, emlp_b1, emlp_w2T, emlp_b2, bufB, parts, NE, 512, 512);
    // 4) finalize T2 stats
    hipLaunchKernelGGL(stats_finalize_kernel, dim3((NE + 255) / 256), dim3(256), 0, stream,
                       parts, stats, NE);

    // 5) grid_proj -> bufC
    hipLaunchKernelGGL(gemm_bt_kernel<0>, dim3(4, NG / 128), dim3(256), 0, stream,
                       grid_bf, geA_T, nf, bufC, NG, 512, 512, nf, nf, (float*)nullptr);
    // 6) mesh_proj -> bufD
    hipLaunchKernelGGL(gemm_bt_kernel<0>, dim3(4, (NM + 127) / 128), dim3(256), 0, stream,
                       mesh_bf, geB_T, nf, bufD, NM, 512, 512, nf, nf, (float*)nullptr);
    // 7) H2 = relu( LNfold(T2)@geC' + grid_proj[recv] + mesh_proj[send] + ge_b1 ) -> bufA
    hipLaunchKernelGGL((gemm256_kernel<4, 0>), dim3(4, NE / 256), dim3(512), 0, stream,
                       bufB, geC_T, ge_b1, bufA, NE, 512, 512,
                       bufC, bufD, send, recv, stats, uvecW, vvecW, nfp);
    // 8) T5 = H2 @ ge_w2 + b2 -> bufB, with stats partials
    hipLaunchKernelGGL((gemm256_kernel<1, 1>), dim3(4, NE / 256), dim3(512), 0, stream,
                       bufA, ge_w2T, ge_b2, bufB, NE, 512, 512,
                       nbf, nbf, ni, ni, nst, nf, nf, parts);
    // 9) finalize T5 stats
    hipLaunchKernelGGL(stats_finalize_kernel, dim3((NE + 255) / 256), dim3(256), 0, stream,
                       parts, stats, NE);
    // 10) X2 = cat(grid_bf, segment_sum(LN(T5))) -> bufA
    hipLaunchKernelGGL(aggregate_kernel, dim3(NG / 4), dim3(256), 0, stream,
                       bufB, stats, ge_g, ge_be, grid_bf, csr_off, csr_edge, bufA, NG);

    // 11) H3 = relu(X2 @ gn_w1 + b1) -> bufC
    hipLaunchKernelGGL(gemm_bt_kernel<2>, dim3(4, NG / 128), dim3(256), 0, stream,
                       bufA, gn_w1T, gn_b1, bufC, NG, 512, 1024, nf, nf, (float*)nullptr);
    // 12) T8 = H3 @ gn_w2 + b2 -> bufB
    hipLaunchKernelGGL(gemm_bt_kernel<1>, dim3(4, NG / 128), dim3(256), 0, stream,
                       bufC, gn_w2T, gn_b2, bufB, NG, 512, 512, nf, nf, (float*)nullptr);
    // 13) latent = grid_bf + LN(T8)*g+b -> bufA
    hipLaunchKernelGGL(ln_resid_kernel, dim3(NG / 4), dim3(256), 0, stream,
                       bufB, gn_g, gn_be, bufA, grid_bf, NG);

    // 14) H4 = relu(latent @ fin_w1 + b1) -> bufC
    hipLaunchKernelGGL(gemm_bt_kernel<2>, dim3(4, NG / 128), dim3(256), 0, stream,
                       bufA, fin_w1T, fin_b1, bufC, NG, 512, 512, nf, nf, (float*)nullptr);
    // 15) out = LN(H4 @ fin_w2 + b2)*fg+fb -> d_out (f32)
    hipLaunchKernelGGL(gemm_bt_kernel<5>, dim3(1, NG / 128), dim3(256), 0, stream,
                       bufC, fin_w2T, fin_b2, (bf16*)nullptr, NG, 128, 512,
                       fin_g, fin_be, (float*)d_out);
}

// Round 13
// 381.239 us; speedup vs baseline: 1.0639x; 1.0639x over previous
//
#include <hip/hip_runtime.h>
#include <hip/hip_bf16.h>
#include <stdint.h>

#define LN_EPS 1e-5f

typedef __hip_bfloat16 bf16;
typedef short short8 __attribute__((ext_vector_type(8)));
typedef short short4v __attribute__((ext_vector_type(4)));
typedef float f32x4 __attribute__((ext_vector_type(4)));

static __device__ __forceinline__ float bf2f(short s) {
    unsigned int u = ((unsigned int)(unsigned short)s) << 16;
    return __uint_as_float(u);
}
static __device__ __forceinline__ short f2bf(float x) {
    __hip_bfloat16 h = __float2bfloat16(x);
    return *reinterpret_cast<short*>(&h);
}

// async global->LDS, 16B per lane; LDS dest = wave-uniform base + lane*16
static __device__ __forceinline__ void gload16(const void* g, void* l) {
    __builtin_amdgcn_global_load_lds((const __attribute__((address_space(1))) void*)g,
                                     (__attribute__((address_space(3))) void*)l, 16, 0, 0);
}

// ---------------- weight transpose + bf16 convert (+ optional per-k scale) ----------------
struct TDesc { const float* src; bf16* dst; int K; int N; int kOff; const float* scale; };
struct TDescs { TDesc d[9]; };

__global__ void transpose_all_kernel(TDescs descs) {
    TDesc t = descs.d[blockIdx.z];
    int kb = blockIdx.x * 32, nb = blockIdx.y * 32;
    if (kb >= t.K || nb >= t.N) return;
    __shared__ float tile[32][33];
    int tx = threadIdx.x & 31, ty = threadIdx.x >> 5;
    for (int i = ty; i < 32; i += 8) {
        int k = kb + i, n = nb + tx;
        float v = (k < t.K && n < t.N) ? t.src[(size_t)(t.kOff + k) * t.N + n] : 0.f;
        if (t.scale && k < t.K) v *= t.scale[k];
        tile[i][tx] = v;
    }
    __syncthreads();
    for (int i = ty; i < 32; i += 8) {
        int n = nb + i, k = kb + tx;
        if (n < t.N && k < t.K)
            t.dst[(size_t)n * t.K + k] = __float2bfloat16(tile[tx][i]);
    }
}

// u[n] = sum_k g[k]*W[1024+k][n], v[n] = sum_k beta[k]*W[1024+k][n]
__global__ void uv_kernel(const float* __restrict__ W, const float* __restrict__ g,
                          const float* __restrict__ be, float* __restrict__ u,
                          float* __restrict__ v) {
    int n = blockIdx.x * 256 + threadIdx.x;
    if (n >= 512) return;
    float su = 0.f, sv = 0.f;
    for (int k = 0; k < 512; k++) {
        float w = W[(size_t)(1024 + k) * 512 + n];
        su += g[k] * w;
        sv += be[k] * w;
    }
    u[n] = su;
    v[n] = sv;
}

// ---------------- f32 -> bf16 convert ----------------
__global__ void cvt_bf16_kernel(const float* __restrict__ src, bf16* __restrict__ dst, int n) {
    int i = blockIdx.x * 256 + threadIdx.x;
    int idx = i * 4;
    if (idx >= n) return;
    float4 v = *(const float4*)(src + idx);
    dst[idx + 0] = __float2bfloat16(v.x);
    dst[idx + 1] = __float2bfloat16(v.y);
    dst[idx + 2] = __float2bfloat16(v.z);
    dst[idx + 3] = __float2bfloat16(v.w);
}

// ---------------- stats finalize: stats[r] = {mu, rs} from 8 partials (4 blk x 2 wn) ----------------
__global__ void stats_finalize_kernel(const float2* __restrict__ partials,
                                      float2* __restrict__ stats, int R) {
    int r = blockIdx.x * 256 + threadIdx.x;
    if (r >= R) return;
    float s = 0.f, q = 0.f;
#pragma unroll
    for (int i = 0; i < 8; i++) {
        float2 pp = partials[(size_t)r * 8 + i];
        s += pp.x; q += pp.y;
    }
    float mu = s * (1.f / 512.f);
    float var = q * (1.f / 512.f) - mu * mu;
    stats[r] = make_float2(mu, rsqrtf(var + LN_EPS));
}

// ============ T2 fused: C = relu(attr@w1+b1) @ BT^T + b2, with stats partials ============
// BM=256, BN=128, BK=64, 512 thr / 8 waves. A-tile (H1) computed ON THE FLY from
// attr (4-wide) + w1 slice, in TWO 4-col halves (register-lean: fits the 64-VGPR
// half of the unified 128-reg budget; acc lives in the AGPR half), ds_written
// into swizzled LDS; B staged via gload16.
__global__ __launch_bounds__(512, 4) void t2_fused_kernel(
    const float* __restrict__ attr, const float* __restrict__ w1,
    const float* __restrict__ b1, const bf16* __restrict__ BT,
    const float* __restrict__ bias, bf16* __restrict__ C,
    float2* __restrict__ partials, int M, int N, int K) {
    __shared__ short SMEM[384 * 64];   // 48 KB: rows 0-255 H1, 256-383 B
    const int t = threadIdx.x;
    const int lane = t & 63, w = t >> 6;
    const int wm = w >> 1, wn = w & 1;
    const int lr = lane & 15, lh = lane >> 4;

    // m204 bijective XCD swizzle
    int gx = gridDim.x;
    int nwg = gx * gridDim.y;
    int orig = blockIdx.y * gx + blockIdx.x;
    int q = nwg >> 3, r = nwg & 7;
    int xcd = orig & 7, loc = orig >> 3;
    int wg = (xcd < r ? xcd * (q + 1) : r * (q + 1) + (xcd - r) * q) + loc;
    int bx = wg % gx, by = wg / gx;
    const int row0 = by * 256;
    const int col0 = bx * 128;

    // H1 on-the-fly mapping: colgrp = t&7 (8 cols), rowblk = t>>3 (4 rows)
    const int cg = t & 7;
    const int rowblk = t >> 3;
    float av[4][4];
#pragma unroll
    for (int rr = 0; rr < 4; rr++) {
        int e = row0 + rowblk * 4 + rr; if (e >= M) e = M - 1;
        float4 a = *(const float4*)(attr + (size_t)e * 4);
        av[rr][0] = a.x; av[rr][1] = a.y; av[rr][2] = a.z; av[rr][3] = a.w;
    }

    // B staging: wave w stages B rows [w*16, w*16+16)
    const int sr3 = lane >> 3;
    const int su = (lane & 7) ^ sr3;
    const int scol = su * 8;
    const bf16* gbP[2];
#pragma unroll
    for (int c = 0; c < 2; c++) {
        int rb = col0 + w * 16 + c * 8 + sr3; if (rb >= N) rb = N - 1;
        gbP[c] = BT + (size_t)rb * K + scol;
    }

    f32x4 acc[4][4];
#pragma unroll
    for (int i = 0; i < 4; i++)
#pragma unroll
        for (int j = 0; j < 4; j++) acc[i][j] = {0.f, 0.f, 0.f, 0.f};

    for (int k0 = 0; k0 < K; k0 += 64) {
        // B async stage
#pragma unroll
        for (int c = 0; c < 2; c++)
            gload16(gbP[c] + k0, SMEM + (256 + w * 16 + c * 8) * 64);
        // H1 compute in two 4-col halves (register-lean)
#pragma unroll
        for (int hf = 0; hf < 2; hf++) {
            int kc = k0 + cg * 8 + hf * 4;
            float4 bb = *(const float4*)(b1 + kc);
            float4 w0 = *(const float4*)(w1 + 0 * 512 + kc);
            float4 w1r = *(const float4*)(w1 + 1 * 512 + kc);
            float4 w2r = *(const float4*)(w1 + 2 * 512 + kc);
            float4 w3r = *(const float4*)(w1 + 3 * 512 + kc);
#pragma unroll
            for (int rr = 0; rr < 4; rr++) {
                int row = rowblk * 4 + rr;
                float c0 = bb.x + av[rr][0] * w0.x + av[rr][1] * w1r.x + av[rr][2] * w2r.x + av[rr][3] * w3r.x;
                float c1 = bb.y + av[rr][0] * w0.y + av[rr][1] * w1r.y + av[rr][2] * w2r.y + av[rr][3] * w3r.y;
                float c2 = bb.z + av[rr][0] * w0.z + av[rr][1] * w1r.z + av[rr][2] * w2r.z + av[rr][3] * w3r.z;
                float c3 = bb.w + av[rr][0] * w0.w + av[rr][1] * w1r.w + av[rr][2] * w2r.w + av[rr][3] * w3r.w;
                short4v h;
                h[0] = f2bf(fmaxf(c0, 0.f));
                h[1] = f2bf(fmaxf(c1, 0.f));
                h[2] = f2bf(fmaxf(c2, 0.f));
                h[3] = f2bf(fmaxf(c3, 0.f));
                *(short4v*)&SMEM[row * 64 + ((cg ^ (row & 7)) * 8) + hf * 4] = h;
            }
        }
        __syncthreads();
#pragma unroll
        for (int kk = 0; kk < 64; kk += 32) {
            short8 af[4], bfv[4];
#pragma unroll
            for (int mf = 0; mf < 4; mf++) {
                int rowa = wm * 64 + mf * 16 + lr;
                int ua = ((kk >> 3) + lh) ^ (rowa & 7);
                af[mf] = *(const short8*)&SMEM[rowa * 64 + ua * 8];
            }
#pragma unroll
            for (int nf = 0; nf < 4; nf++) {
                int rowb = 256 + wn * 64 + nf * 16 + lr;
                int ub = ((kk >> 3) + lh) ^ (rowb & 7);
                bfv[nf] = *(const short8*)&SMEM[rowb * 64 + ub * 8];
            }
#pragma unroll
            for (int mf = 0; mf < 4; mf++)
#pragma unroll
                for (int nf = 0; nf < 4; nf++)
                    acc[mf][nf] = __builtin_amdgcn_mfma_f32_16x16x32_bf16(
                        af[mf], bfv[nf], acc[mf][nf], 0, 0, 0);
        }
        __syncthreads();
    }

    // epilogue: +bias, store, per-row stats partials (slot = bx*2 + wn)
    short* Cw = SMEM + w * (32 * 66);
    const int rgrp = lane >> 3, u = lane & 7;
#pragma unroll
    for (int hp = 0; hp < 2; hp++) {
#pragma unroll
        for (int mf2 = 0; mf2 < 2; mf2++) {
            int mf = hp * 2 + mf2;
#pragma unroll
            for (int nf = 0; nf < 4; nf++)
#pragma unroll
                for (int r2 = 0; r2 < 4; r2++) {
                    int rl = mf2 * 16 + lh * 4 + r2;
                    Cw[rl * 66 + nf * 16 + lr] = f2bf(acc[mf][nf][r2]);
                }
        }
#pragma unroll
        for (int rr = 0; rr < 4; rr++) {
            int rl = rr * 8 + rgrp;
            int grow = row0 + wm * 64 + hp * 32 + rl;
            int gcol = col0 + wn * 64 + u * 8;
            short8 vv = *(const short8*)&Cw[rl * 66 + u * 8];
            float vf[8];
#pragma unroll
            for (int j = 0; j < 8; j++) vf[j] = bf2f(vv[j]);
            float4 c0 = *(const float4*)(bias + gcol);
            float4 c1 = *(const float4*)(bias + gcol + 4);
            float bb[8] = {c0.x, c0.y, c0.z, c0.w, c1.x, c1.y, c1.z, c1.w};
#pragma unroll
            for (int j = 0; j < 8; j++) vf[j] += bb[j];
            float s1 = 0.f, s2 = 0.f;
#pragma unroll
            for (int j = 0; j < 8; j++) { s1 += vf[j]; s2 += vf[j] * vf[j]; }
            s1 += __shfl_xor(s1, 1, 64); s2 += __shfl_xor(s2, 1, 64);
            s1 += __shfl_xor(s1, 2, 64); s2 += __shfl_xor(s2, 2, 64);
            s1 += __shfl_xor(s1, 4, 64); s2 += __shfl_xor(s2, 4, 64);
            if (u == 0 && grow < M)
                partials[(size_t)grow * 8 + bx * 2 + wn] = make_float2(s1, s2);
            short8 o;
#pragma unroll
            for (int j = 0; j < 8; j++) o[j] = f2bf(vf[j]);
            if (grow < M && gcol < N)
                *(short8*)(C + (size_t)grow * N + gcol) = o;
        }
    }
}

// ============ gemm256: BM=256, BN=128, BK=64, 512 thr / 8 waves ============
// EPI: 1 +bias | 4 LN-fold + gather + relu.  STATS: write per-row {sum,sumsq} partials.
template <int EPI, int STATS>
__global__ __launch_bounds__(512, 4) void gemm256_kernel(
    const bf16* __restrict__ A, const bf16* __restrict__ BT,
    const float* __restrict__ bias, bf16* __restrict__ C, int M, int N, int K,
    const bf16* __restrict__ gridp, const bf16* __restrict__ meshp,
    const int* __restrict__ send, const int* __restrict__ recv,
    const float2* __restrict__ stats, const float* __restrict__ uvec,
    const float* __restrict__ vvec, float2* __restrict__ partials) {
    __shared__ short SMEM[384 * 64];   // 48 KB
    const int t = threadIdx.x;
    const int lane = t & 63, w = t >> 6;
    const int wm = w >> 1, wn = w & 1;
    const int lr = lane & 15, lh = lane >> 4;

    int gx = gridDim.x;
    int nwg = gx * gridDim.y;
    int orig = blockIdx.y * gx + blockIdx.x;
    int q = nwg >> 3, r = nwg & 7;
    int xcd = orig & 7, loc = orig >> 3;
    int wg = (xcd < r ? xcd * (q + 1) : r * (q + 1) + (xcd - r) * q) + loc;
    int bx = wg % gx, by = wg / gx;
    const int row0 = by * 256;
    const int col0 = bx * 128;

    const int sr3 = lane >> 3;
    const int su = (lane & 7) ^ sr3;
    const int scol = su * 8;
    const bf16* gp6[6];
#pragma unroll
    for (int i = 0; i < 6; i++) {
        int rr = w * 48 + i * 8 + sr3;
        if (rr < 256) {
            int ra = row0 + rr; if (ra >= M) ra = M - 1;
            gp6[i] = A + (size_t)ra * K + scol;
        } else {
            int rb = col0 + (rr - 256); if (rb >= N) rb = N - 1;
            gp6[i] = BT + (size_t)rb * K + scol;
        }
    }

    f32x4 acc[4][4];
#pragma unroll
    for (int i = 0; i < 4; i++)
#pragma unroll
        for (int j = 0; j < 4; j++) acc[i][j] = {0.f, 0.f, 0.f, 0.f};

    for (int k0 = 0; k0 < K; k0 += 64) {
#pragma unroll
        for (int i = 0; i < 6; i++)
            gload16(gp6[i] + k0, SMEM + (w * 48 + i * 8) * 64);
        __syncthreads();
#pragma unroll
        for (int kk = 0; kk < 64; kk += 32) {
            short8 af[4], bfv[4];
#pragma unroll
            for (int mf = 0; mf < 4; mf++) {
                int rowa = wm * 64 + mf * 16 + lr;
                int ua = ((kk >> 3) + lh) ^ (rowa & 7);
                af[mf] = *(const short8*)&SMEM[rowa * 64 + ua * 8];
            }
#pragma unroll
            for (int nf = 0; nf < 4; nf++) {
                int rowb = 256 + wn * 64 + nf * 16 + lr;
                int ub = ((kk >> 3) + lh) ^ (rowb & 7);
                bfv[nf] = *(const short8*)&SMEM[rowb * 64 + ub * 8];
            }
#pragma unroll
            for (int mf = 0; mf < 4; mf++)
#pragma unroll
                for (int nf = 0; nf < 4; nf++)
                    acc[mf][nf] = __builtin_amdgcn_mfma_f32_16x16x32_bf16(
                        af[mf], bfv[nf], acc[mf][nf], 0, 0, 0);
        }
        __syncthreads();
    }

    short* Cw = SMEM + w * (32 * 66);
    const int rgrp = lane >> 3, u = lane & 7;
#pragma unroll
    for (int hp = 0; hp < 2; hp++) {
#pragma unroll
        for (int mf2 = 0; mf2 < 2; mf2++) {
            int mf = hp * 2 + mf2;
#pragma unroll
            for (int nf = 0; nf < 4; nf++)
#pragma unroll
                for (int r2 = 0; r2 < 4; r2++) {
                    int rl = mf2 * 16 + lh * 4 + r2;
                    Cw[rl * 66 + nf * 16 + lr] = f2bf(acc[mf][nf][r2]);
                }
        }
#pragma unroll
        for (int rr = 0; rr < 4; rr++) {
            int rl = rr * 8 + rgrp;
            int grow = row0 + wm * 64 + hp * 32 + rl;
            int gcol = col0 + wn * 64 + u * 8;
            short8 vv = *(const short8*)&Cw[rl * 66 + u * 8];
            float vf[8];
#pragma unroll
            for (int j = 0; j < 8; j++) vf[j] = bf2f(vv[j]);
            if (EPI == 4) {
                int e = grow < M ? grow : M - 1;
                float2 st = stats[e];
                float rs = st.y, mrs = st.x * st.y;
                float4 u0 = *(const float4*)(uvec + gcol), u1 = *(const float4*)(uvec + gcol + 4);
                float4 v0 = *(const float4*)(vvec + gcol), v1 = *(const float4*)(vvec + gcol + 4);
                float uu[8] = {u0.x, u0.y, u0.z, u0.w, u1.x, u1.y, u1.z, u1.w};
                float vvv[8] = {v0.x, v0.y, v0.z, v0.w, v1.x, v1.y, v1.z, v1.w};
#pragma unroll
                for (int j = 0; j < 8; j++) vf[j] = rs * vf[j] - mrs * uu[j] + vvv[j];
            }
            {
                float4 c0 = *(const float4*)(bias + gcol);
                float4 c1 = *(const float4*)(bias + gcol + 4);
                float bb[8] = {c0.x, c0.y, c0.z, c0.w, c1.x, c1.y, c1.z, c1.w};
#pragma unroll
                for (int j = 0; j < 8; j++) vf[j] += bb[j];
            }
            if (EPI == 4) {
                int e = grow < M ? grow : M - 1;
                int rn = recv[e], sn = send[e];
                short8 gp = *(const short8*)(gridp + (size_t)rn * 512 + gcol);
                short8 mp = *(const short8*)(meshp + (size_t)sn * 512 + gcol);
#pragma unroll
                for (int j = 0; j < 8; j++) vf[j] += bf2f(gp[j]) + bf2f(mp[j]);
#pragma unroll
                for (int j = 0; j < 8; j++) vf[j] = fmaxf(vf[j], 0.f);
            }
            if (STATS) {
                float s1 = 0.f, s2 = 0.f;
#pragma unroll
                for (int j = 0; j < 8; j++) { s1 += vf[j]; s2 += vf[j] * vf[j]; }
                s1 += __shfl_xor(s1, 1, 64); s2 += __shfl_xor(s2, 1, 64);
                s1 += __shfl_xor(s1, 2, 64); s2 += __shfl_xor(s2, 2, 64);
                s1 += __shfl_xor(s1, 4, 64); s2 += __shfl_xor(s2, 4, 64);
                if (u == 0 && grow < M)
                    partials[(size_t)grow * 8 + bx * 2 + wn] = make_float2(s1, s2);
            }
            short8 o;
#pragma unroll
            for (int j = 0; j < 8; j++) o[j] = f2bf(vf[j]);
            if (grow < M && gcol < N)
                *(short8*)(C + (size_t)grow * N + gcol) = o;
        }
    }
}

// ============ gemm_bt: 128x128, R5 single-buffer loop ============
// EPI: 0 none | 1 +bias | 2 +bias+relu | 5 final-LN (N==128, f32 out)
template <int EPI>
__global__ __launch_bounds__(256, 4) void gemm_bt_kernel(
    const bf16* __restrict__ A, const bf16* __restrict__ BT,
    const float* __restrict__ bias, bf16* __restrict__ C, int M, int N, int K,
    const float* __restrict__ fg, const float* __restrict__ fb,
    float* __restrict__ OutF) {
    __shared__ short SMEM[132 * 128 + 64];
    const int t = threadIdx.x;
    const int lane = t & 63, w = t >> 6;
    const int wm = w >> 1, wn = w & 1;
    const int lr = lane & 15, lh = lane >> 4;

    int gx = gridDim.x;
    int nwg = gx * gridDim.y;
    int orig = blockIdx.y * gx + blockIdx.x;
    int q = nwg >> 3, r = nwg & 7;
    int xcd = orig & 7, loc = orig >> 3;
    int wg = (xcd < r ? xcd * (q + 1) : r * (q + 1) + (xcd - r) * q) + loc;
    int bx = wg % gx, by = wg / gx;
    const int row0 = by * 128;
    const int col0 = bx * 128;

    const int sr3 = lane >> 3;
    const int su = (lane & 7) ^ sr3;
    const int srow = w * 32 + sr3;
    const int scol = su * 8;
    const bf16* gaP[4];
    const bf16* gbP[4];
#pragma unroll
    for (int i = 0; i < 4; i++) {
        int ra = row0 + srow + i * 8; if (ra >= M) ra = M - 1;
        int rb = col0 + srow + i * 8; if (rb >= N) rb = N - 1;
        gaP[i] = A + (size_t)ra * K + scol;
        gbP[i] = BT + (size_t)rb * K + scol;
    }

    f32x4 acc[4][4];
#pragma unroll
    for (int i = 0; i < 4; i++)
#pragma unroll
        for (int j = 0; j < 4; j++) acc[i][j] = {0.f, 0.f, 0.f, 0.f};

    for (int k0 = 0; k0 < K; k0 += 64) {
        short* la = SMEM + w * 32 * 64;
        short* lb = la + 8192;
#pragma unroll
        for (int i = 0; i < 4; i++) {
            gload16(gaP[i] + k0, la + i * 8 * 64);
            gload16(gbP[i] + k0, lb + i * 8 * 64);
        }
        __syncthreads();
#pragma unroll
        for (int kk = 0; kk < 64; kk += 32) {
            short8 af[4], bfv[4];
#pragma unroll
            for (int mf = 0; mf < 4; mf++) {
                int rowa = wm * 64 + mf * 16 + lr;
                int ua = ((kk >> 3) + lh) ^ (rowa & 7);
                af[mf] = *(const short8*)&SMEM[rowa * 64 + ua * 8];
            }
#pragma unroll
            for (int nf = 0; nf < 4; nf++) {
                int rowb = wn * 64 + nf * 16 + lr;
                int ub = ((kk >> 3) + lh) ^ (rowb & 7);
                bfv[nf] = *(const short8*)&SMEM[8192 + rowb * 64 + ub * 8];
            }
#pragma unroll
            for (int mf = 0; mf < 4; mf++)
#pragma unroll
                for (int nf = 0; nf < 4; nf++)
                    acc[mf][nf] = __builtin_amdgcn_mfma_f32_16x16x32_bf16(
                        af[mf], bfv[nf], acc[mf][nf], 0, 0, 0);
        }
        __syncthreads();
    }

    if (EPI == 5) {
        short* Cs = SMEM;   // [128][132]
#pragma unroll
        for (int nf = 0; nf < 4; nf++) {
            float bv = bias[wn * 64 + nf * 16 + lr];
#pragma unroll
            for (int mf = 0; mf < 4; mf++)
#pragma unroll
                for (int r2 = 0; r2 < 4; r2++) {
                    int rl = wm * 64 + mf * 16 + lh * 4 + r2;
                    Cs[rl * 132 + wn * 64 + nf * 16 + lr] = f2bf(acc[mf][nf][r2] + bv);
                }
        }
        __syncthreads();
        int rl = w * 32 + (lane >> 1);
        int half = lane & 1;
        short8 vs[8];
        float s = 0.f, s2 = 0.f;
#pragma unroll
        for (int j8 = 0; j8 < 8; j8++) {
            vs[j8] = *(const short8*)&Cs[rl * 132 + half * 64 + j8 * 8];
#pragma unroll
            for (int j = 0; j < 8; j++) {
                float f = bf2f(vs[j8][j]);
                s += f; s2 += f * f;
            }
        }
        s += __shfl_xor(s, 1, 64);
        s2 += __shfl_xor(s2, 1, 64);
        float mu = s * (1.f / 128.f);
        float var = s2 * (1.f / 128.f) - mu * mu;
        float rs = rsqrtf(var + LN_EPS);
        int grow = row0 + rl;
#pragma unroll
        for (int j8 = 0; j8 < 8; j8++) {
            int c0 = half * 64 + j8 * 8;
            float4 g0 = *(const float4*)(fg + c0), g1 = *(const float4*)(fg + c0 + 4);
            float4 b0 = *(const float4*)(fb + c0), b1v = *(const float4*)(fb + c0 + 4);
            float gg[8] = {g0.x, g0.y, g0.z, g0.w, g1.x, g1.y, g1.z, g1.w};
            float bb[8] = {b0.x, b0.y, b0.z, b0.w, b1v.x, b1v.y, b1v.z, b1v.w};
            float4 o0, o1;
#pragma unroll
            for (int j = 0; j < 8; j++) {
                float y = (bf2f(vs[j8][j]) - mu) * rs * gg[j] + bb[j];
                if (j < 4) ((float*)&o0)[j] = y; else ((float*)&o1)[j - 4] = y;
            }
            *(float4*)(OutF + (size_t)grow * 128 + c0) = o0;
            *(float4*)(OutF + (size_t)grow * 128 + c0 + 4) = o1;
        }
        return;
    }

    short* Cw = SMEM + w * (32 * 66);
    const int rgrp = lane >> 3, u = lane & 7;
#pragma unroll
    for (int hp = 0; hp < 2; hp++) {
#pragma unroll
        for (int mf2 = 0; mf2 < 2; mf2++) {
            int mf = hp * 2 + mf2;
#pragma unroll
            for (int nf = 0; nf < 4; nf++)
#pragma unroll
                for (int r2 = 0; r2 < 4; r2++) {
                    int rl = mf2 * 16 + lh * 4 + r2;
                    Cw[rl * 66 + nf * 16 + lr] = f2bf(acc[mf][nf][r2]);
                }
        }
#pragma unroll
        for (int rr = 0; rr < 4; rr++) {
            int rl = rr * 8 + rgrp;
            int grow = row0 + wm * 64 + hp * 32 + rl;
            int gcol = col0 + wn * 64 + u * 8;
            short8 vv = *(const short8*)&Cw[rl * 66 + u * 8];
            float vf[8];
#pragma unroll
            for (int j = 0; j < 8; j++) vf[j] = bf2f(vv[j]);
            if (EPI >= 1) {
                float4 c0 = *(const float4*)(bias + gcol);
                float4 c1 = *(const float4*)(bias + gcol + 4);
                float bb[8] = {c0.x, c0.y, c0.z, c0.w, c1.x, c1.y, c1.z, c1.w};
#pragma unroll
                for (int j = 0; j < 8; j++) vf[j] += bb[j];
            }
            if (EPI == 2) {
#pragma unroll
                for (int j = 0; j < 8; j++) vf[j] = fmaxf(vf[j], 0.f);
            }
            short8 o;
#pragma unroll
            for (int j = 0; j < 8; j++) o[j] = f2bf(vf[j]);
            if (grow < M && gcol < N)
                *(short8*)(C + (size_t)grow * N + gcol) = o;
        }
    }
}

// ---------------- LayerNorm with residual add (DN=512) ----------------
__global__ void ln_resid_kernel(const bf16* __restrict__ X, const float* __restrict__ gw,
                                const float* __restrict__ bw, bf16* __restrict__ outb,
                                const bf16* __restrict__ resid, int R) {
    int row = blockIdx.x * 4 + (threadIdx.x >> 6);
    if (row >= R) return;
    int lane = threadIdx.x & 63;
    short8 t8 = *(const short8*)(X + (size_t)row * 512 + lane * 8);
    float v[8];
#pragma unroll
    for (int j = 0; j < 8; j++) v[j] = bf2f(t8[j]);
    float s = 0.f, s2 = 0.f;
#pragma unroll
    for (int j = 0; j < 8; j++) { s += v[j]; s2 += v[j] * v[j]; }
#pragma unroll
    for (int o = 32; o > 0; o >>= 1) {
        s += __shfl_xor(s, o, 64);
        s2 += __shfl_xor(s2, o, 64);
    }
    float mu = s * (1.f / 512.f);
    float var = s2 * (1.f / 512.f) - mu * mu;
    float rs = rsqrtf(var + LN_EPS);
    int d0 = lane * 8;
    short8 rv = *(const short8*)(resid + (size_t)row * 512 + d0);
    short8 o;
#pragma unroll
    for (int j = 0; j < 8; j++) {
        float y = (v[j] - mu) * rs * gw[d0 + j] + bw[d0 + j];
        o[j] = f2bf(bf2f(rv[j]) + y);
    }
    *(short8*)(outb + (size_t)row * 512 + d0) = o;
}

// ---------------- CSR build ----------------
__global__ void degree_kernel(const int* __restrict__ recv, int* __restrict__ deg, int E) {
    int e = blockIdx.x * 256 + threadIdx.x;
    if (e < E) atomicAdd(&deg[recv[e]], 1);
}

__global__ void scan_kernel(const int* __restrict__ deg, int* __restrict__ off) {
    __shared__ int partial[1024];
    int t = threadIdx.x;
    int base = t * 16;
    int v[16];
    int s = 0;
#pragma unroll
    for (int i = 0; i < 16; i++) { v[i] = deg[base + i]; s += v[i]; }
    partial[t] = s;
    __syncthreads();
    for (int o = 1; o < 1024; o <<= 1) {
        int x = (t >= o) ? partial[t - o] : 0;
        __syncthreads();
        partial[t] += x;
        __syncthreads();
    }
    int run = (t == 0) ? 0 : partial[t - 1];
#pragma unroll
    for (int i = 0; i < 16; i++) { off[base + i] = run; run += v[i]; }
    if (t == 1023) off[16384] = run;
}

__global__ void scatter_kernel(const int* __restrict__ recv, const int* __restrict__ off,
                               int* __restrict__ cnt, int* __restrict__ edges, int E) {
    int e = blockIdx.x * 256 + threadIdx.x;
    if (e < E) {
        int r = recv[e];
        int p = atomicAdd(&cnt[r], 1);
        edges[off[r] + p] = e;
    }
}

// ---------------- aggregate LN(msg) by receiver + build X2 = cat(grid_bf, aggr) ----------------
__global__ void aggregate_kernel(const bf16* __restrict__ T5, const float2* __restrict__ stats,
                                 const float* __restrict__ gw, const float* __restrict__ bw,
                                 const bf16* __restrict__ gridb,
                                 const int* __restrict__ off, const int* __restrict__ edges,
                                 bf16* __restrict__ X2, int G) {
    int g = blockIdx.x * 4 + (threadIdx.x >> 6);
    if (g >= G) return;
    int lane = threadIdx.x & 63;
    int d0 = lane * 8;
    float gg[8], bb[8];
    {
        float4 a = *(const float4*)(gw + d0), b = *(const float4*)(gw + d0 + 4);
        gg[0]=a.x; gg[1]=a.y; gg[2]=a.z; gg[3]=a.w; gg[4]=b.x; gg[5]=b.y; gg[6]=b.z; gg[7]=b.w;
        float4 c = *(const float4*)(bw + d0), d = *(const float4*)(bw + d0 + 4);
        bb[0]=c.x; bb[1]=c.y; bb[2]=c.z; bb[3]=c.w; bb[4]=d.x; bb[5]=d.y; bb[6]=d.z; bb[7]=d.w;
    }
    float s[8] = {0.f, 0.f, 0.f, 0.f, 0.f, 0.f, 0.f, 0.f};
    int a = off[g], b = off[g + 1];
    for (int i = a; i < b; i++) {
        int e = edges[i];
        float2 st = stats[e];
        short8 m = *(const short8*)(T5 + (size_t)e * 512 + d0);
#pragma unroll
        for (int j = 0; j < 8; j++)
            s[j] += (bf2f(m[j]) - st.x) * st.y * gg[j] + bb[j];
    }
    *(short8*)(X2 + (size_t)g * 1024 + d0) = *(const short8*)(gridb + (size_t)g * 512 + d0);
    short8 o;
#pragma unroll
    for (int j = 0; j < 8; j++) o[j] = f2bf(s[j]);
    *(short8*)(X2 + (size_t)g * 1024 + 512 + d0) = o;
}

extern "C" void kernel_launch(void* const* d_in, const int* in_sizes, int n_in,
                              void* d_out, int out_size, void* d_ws, size_t ws_size,
                              hipStream_t stream) {
    const int NM = 2562, NG = 16384, NE = 49152;
    const float* mesh   = (const float*)d_in[0];
    const float* grid   = (const float*)d_in[1];
    const float* attr   = (const float*)d_in[2];
    const int*   eidx   = (const int*)d_in[3];
    const int*   send   = eidx;
    const int*   recv   = eidx + NE;
    const float* emlp_w1 = (const float*)d_in[4];
    const float* emlp_b1 = (const float*)d_in[5];
    const float* emlp_w2 = (const float*)d_in[6];
    const float* emlp_b2 = (const float*)d_in[7];
    const float* emlp_g  = (const float*)d_in[8];
    const float* emlp_be = (const float*)d_in[9];
    const float* ge_w1 = (const float*)d_in[10];
    const float* ge_b1 = (const float*)d_in[11];
    const float* ge_w2 = (const float*)d_in[12];
    const float* ge_b2 = (const float*)d_in[13];
    const float* ge_g  = (const float*)d_in[14];
    const float* ge_be = (const float*)d_in[15];
    const float* gn_w1 = (const float*)d_in[16];
    const float* gn_b1 = (const float*)d_in[17];
    const float* gn_w2 = (const float*)d_in[18];
    const float* gn_b2 = (const float*)d_in[19];
    const float* gn_g  = (const float*)d_in[20];
    const float* gn_be = (const float*)d_in[21];
    const float* fin_w1 = (const float*)d_in[22];
    const float* fin_b1 = (const float*)d_in[23];
    const float* fin_w2 = (const float*)d_in[24];
    const float* fin_b2 = (const float*)d_in[25];
    const float* fin_g  = (const float*)d_in[26];
    const float* fin_be = (const float*)d_in[27];

    char* p = (char*)d_ws;
    auto take = [&](size_t bytes) -> char* {
        char* r = p;
        p += (bytes + 255) & ~(size_t)255;
        return r;
    };
    bf16* emlp_w2T = (bf16*)take((size_t)512 * 512 * 2);
    bf16* geA_T    = (bf16*)take((size_t)512 * 512 * 2);
    bf16* geB_T    = (bf16*)take((size_t)512 * 512 * 2);
    bf16* geC_T    = (bf16*)take((size_t)512 * 512 * 2);   // pre-scaled by emlp_g
    bf16* ge_w2T   = (bf16*)take((size_t)512 * 512 * 2);
    bf16* gn_w1T   = (bf16*)take((size_t)512 * 1024 * 2);
    bf16* gn_w2T   = (bf16*)take((size_t)512 * 512 * 2);
    bf16* fin_w1T  = (bf16*)take((size_t)512 * 512 * 2);
    bf16* fin_w2T  = (bf16*)take((size_t)128 * 512 * 2);
    bf16* grid_bf  = (bf16*)take((size_t)NG * 512 * 2);
    bf16* mesh_bf  = (bf16*)take((size_t)NM * 512 * 2);
    bf16* bufA     = (bf16*)take((size_t)NE * 512 * 2);
    bf16* bufB     = (bf16*)take((size_t)NE * 512 * 2);
    bf16* bufC     = (bf16*)take((size_t)NG * 512 * 2);
    bf16* bufD     = (bf16*)take((size_t)NM * 512 * 2);
    float2* stats  = (float2*)take((size_t)NE * 8);
    float2* parts  = (float2*)take((size_t)NE * 8 * 8);
    float* uvecW   = (float*)take((size_t)512 * 4);
    float* vvecW   = (float*)take((size_t)512 * 4);
    int*  deg      = (int*)take((size_t)NG * 4);
    int*  cnt      = (int*)take((size_t)NG * 4);
    int*  csr_off  = (int*)take((size_t)(NG + 1) * 4);
    int*  csr_edge = (int*)take((size_t)NE * 4);

    const bf16* nbf = nullptr; const int* ni = nullptr;
    const float2* nst = nullptr; const float* nf = nullptr;
    float2* nfp = nullptr;

    // 1) transpose + bf16-convert all GEMM weights (geC pre-scaled by emlp_g)
    TDescs td;
    td.d[0] = {emlp_w2, emlp_w2T, 512, 512, 0, nullptr};
    td.d[1] = {ge_w1,   geA_T,    512, 512, 0, nullptr};
    td.d[2] = {ge_w1,   geB_T,    512, 512, 512, nullptr};
    td.d[3] = {ge_w1,   geC_T,    512, 512, 1024, emlp_g};
    td.d[4] = {ge_w2,   ge_w2T,   512, 512, 0, nullptr};
    td.d[5] = {gn_w1,   gn_w1T,  1024, 512, 0, nullptr};
    td.d[6] = {gn_w2,   gn_w2T,   512, 512, 0, nullptr};
    td.d[7] = {fin_w1,  fin_w1T,  512, 512, 0, nullptr};
    td.d[8] = {fin_w2,  fin_w2T,  512, 128, 0, nullptr};
    hipLaunchKernelGGL(transpose_all_kernel, dim3(32, 16, 9), dim3(256), 0, stream, td);
    hipLaunchKernelGGL(uv_kernel, dim3(2), dim3(256), 0, stream,
                       ge_w1, emlp_g, emlp_be, uvecW, vvecW);

    // 2) bf16 inputs + CSR build
    hipLaunchKernelGGL(cvt_bf16_kernel, dim3((NG * 512 / 4 + 255) / 256), dim3(256), 0, stream,
                       grid, grid_bf, NG * 512);
    hipLaunchKernelGGL(cvt_bf16_kernel, dim3((NM * 512 / 4 + 255) / 256), dim3(256), 0, stream,
                       mesh, mesh_bf, NM * 512);
    hipMemsetAsync(deg, 0, (size_t)NG * 4, stream);
    hipMemsetAsync(cnt, 0, (size_t)NG * 4, stream);
    hipLaunchKernelGGL(degree_kernel, dim3((NE + 255) / 256), dim3(256), 0, stream, recv, deg, NE);
    hipLaunchKernelGGL(scan_kernel, dim3(1), dim3(1024), 0, stream, deg, csr_off);
    hipLaunchKernelGGL(scatter_kernel, dim3((NE + 255) / 256), dim3(256), 0, stream,
                       recv, csr_off, cnt, csr_edge, NE);

    // 3) T2 = relu(attr@emlp_w1+b1) @ emlp_w2 + b2 -> bufB, with stats partials
    hipLaunchKernelGGL(t2_fused_kernel, dim3(4, NE / 256), dim3(512), 0, stream,
                       attr, emlp_w1, emlp_b1, emlp_w2T, emlp_b2, bufB, parts, NE, 512, 512);
    // 4) finalize T2 stats
    hipLaunchKernelGGL(stats_finalize_kernel, dim3((NE + 255) / 256), dim3(256), 0, stream,
                       parts, stats, NE);

    // 5) grid_proj -> bufC
    hipLaunchKernelGGL(gemm_bt_kernel<0>, dim3(4, NG / 128), dim3(256), 0, stream,
                       grid_bf, geA_T, nf, bufC, NG, 512, 512, nf, nf, (float*)nullptr);
    // 6) mesh_proj -> bufD
    hipLaunchKernelGGL(gemm_bt_kernel<0>, dim3(4, (NM + 127) / 128), dim3(256), 0, stream,
                       mesh_bf, geB_T, nf, bufD, NM, 512, 512, nf, nf, (float*)nullptr);
    // 7) H2 = relu( LNfold(T2)@geC' + grid_proj[recv] + mesh_proj[send] + ge_b1 ) -> bufA
    hipLaunchKernelGGL((gemm256_kernel<4, 0>), dim3(4, NE / 256), dim3(512), 0, stream,
                       bufB, geC_T, ge_b1, bufA, NE, 512, 512,
                       bufC, bufD, send, recv, stats, uvecW, vvecW, nfp);
    // 8) T5 = H2 @ ge_w2 + b2 -> bufB, with stats partials
    hipLaunchKernelGGL((gemm256_kernel<1, 1>), dim3(4, NE / 256), dim3(512), 0, stream,
                       bufA, ge_w2T, ge_b2, bufB, NE, 512, 512,
                       nbf, nbf, ni, ni, nst, nf, nf, parts);
    // 9) finalize T5 stats
    hipLaunchKernelGGL(stats_finalize_kernel, dim3((NE + 255) / 256), dim3(256), 0, stream,
                       parts, stats, NE);
    // 10) X2 = cat(grid_bf, segment_sum(LN(T5))) -> bufA
    hipLaunchKernelGGL(aggregate_kernel, dim3(NG / 4), dim3(256), 0, stream,
                       bufB, stats, ge_g, ge_be, grid_bf, csr_off, csr_edge, bufA, NG);

    // 11) H3 = relu(X2 @ gn_w1 + b1) -> bufC
    hipLaunchKernelGGL(gemm_bt_kernel<2>, dim3(4, NG / 128), dim3(256), 0, stream,
                       bufA, gn_w1T, gn_b1, bufC, NG, 512, 1024, nf, nf, (float*)nullptr);
    // 12) T8 = H3 @ gn_w2 + b2 -> bufB
    hipLaunchKernelGGL(gemm_bt_kernel<1>, dim3(4, NG / 128), dim3(256), 0, stream,
                       bufC, gn_w2T, gn_b2, bufB, NG, 512, 512, nf, nf, (float*)nullptr);
    // 13) latent = grid_bf + LN(T8)*g+b -> bufA
    hipLaunchKernelGGL(ln_resid_kernel, dim3(NG / 4), dim3(256), 0, stream,
                       bufB, gn_g, gn_be, bufA, grid_bf, NG);

    // 14) H4 = relu(latent @ fin_w1 + b1) -> bufC
    hipLaunchKernelGGL(gemm_bt_kernel<2>, dim3(4, NG / 128), dim3(256), 0, stream,
                       bufA, fin_w1T, fin_b1, bufC, NG, 512, 512, nf, nf, (float*)nullptr);
    // 15) out = LN(H4 @ fin_w2 + b2)*fg+fb -> d_out (f32)
    hipLaunchKernelGGL(gemm_bt_kernel<5>, dim3(1, NG / 128), dim3(256), 0, stream,
                       bufC, fin_w2T, fin_b2, (bf16*)nullptr, NG, 128, 512,
                       fin_g, fin_be, (float*)d_out);
}

// Round 14
// 350.445 us; speedup vs baseline: 1.1574x; 1.0879x over previous
//
#include <hip/hip_runtime.h>
#include <hip/hip_bf16.h>
#include <stdint.h>

#define LN_EPS 1e-5f

typedef __hip_bfloat16 bf16;
typedef short short8 __attribute__((ext_vector_type(8)));
typedef float f32x4 __attribute__((ext_vector_type(4)));

static __device__ __forceinline__ float bf2f(short s) {
    unsigned int u = ((unsigned int)(unsigned short)s) << 16;
    return __uint_as_float(u);
}
static __device__ __forceinline__ short f2bf(float x) {
    __hip_bfloat16 h = __float2bfloat16(x);
    return *reinterpret_cast<short*>(&h);
}

// async global->LDS, 16B per lane; LDS dest = wave-uniform base + lane*16
static __device__ __forceinline__ void gload16(const void* g, void* l) {
    __builtin_amdgcn_global_load_lds((const __attribute__((address_space(1))) void*)g,
                                     (__attribute__((address_space(3))) void*)l, 16, 0, 0);
}

// ---------------- weight transpose + bf16 convert (+ optional per-k scale) ----------------
struct TDesc { const float* src; bf16* dst; int K; int N; int kOff; const float* scale; };
struct TDescs { TDesc d[9]; };

__global__ void transpose_all_kernel(TDescs descs) {
    TDesc t = descs.d[blockIdx.z];
    int kb = blockIdx.x * 32, nb = blockIdx.y * 32;
    if (kb >= t.K || nb >= t.N) return;
    __shared__ float tile[32][33];
    int tx = threadIdx.x & 31, ty = threadIdx.x >> 5;
    for (int i = ty; i < 32; i += 8) {
        int k = kb + i, n = nb + tx;
        float v = (k < t.K && n < t.N) ? t.src[(size_t)(t.kOff + k) * t.N + n] : 0.f;
        if (t.scale && k < t.K) v *= t.scale[k];
        tile[i][tx] = v;
    }
    __syncthreads();
    for (int i = ty; i < 32; i += 8) {
        int n = nb + i, k = kb + tx;
        if (n < t.N && k < t.K)
            t.dst[(size_t)n * t.K + k] = __float2bfloat16(tile[tx][i]);
    }
}

// u[n] = sum_k g[k]*W[1024+k][n], v[n] = sum_k beta[k]*W[1024+k][n]
__global__ void uv_kernel(const float* __restrict__ W, const float* __restrict__ g,
                          const float* __restrict__ be, float* __restrict__ u,
                          float* __restrict__ v) {
    int n = blockIdx.x * 256 + threadIdx.x;
    if (n >= 512) return;
    float su = 0.f, sv = 0.f;
    for (int k = 0; k < 512; k++) {
        float w = W[(size_t)(1024 + k) * 512 + n];
        su += g[k] * w;
        sv += be[k] * w;
    }
    u[n] = su;
    v[n] = sv;
}

// ---------------- f32 -> bf16 convert ----------------
__global__ void cvt_bf16_kernel(const float* __restrict__ src, bf16* __restrict__ dst, int n) {
    int i = blockIdx.x * 256 + threadIdx.x;
    int idx = i * 4;
    if (idx >= n) return;
    float4 v = *(const float4*)(src + idx);
    dst[idx + 0] = __float2bfloat16(v.x);
    dst[idx + 1] = __float2bfloat16(v.y);
    dst[idx + 2] = __float2bfloat16(v.z);
    dst[idx + 3] = __float2bfloat16(v.w);
}

// ---------------- edge MLP layer 1: one wave per edge row ----------------
__global__ void edge_l1_kernel(const float* __restrict__ attr, const float* __restrict__ w1,
                               const float* __restrict__ b1, bf16* __restrict__ h1, int E) {
    int e = blockIdx.x * 4 + (threadIdx.x >> 6);
    if (e >= E) return;
    int lane = threadIdx.x & 63;
    int d0 = lane * 8;
    float4 a = *(const float4*)(attr + (size_t)e * 4);
    float av[4] = {a.x, a.y, a.z, a.w};
    float s[8];
    {
        float4 c0 = *(const float4*)(b1 + d0), c1 = *(const float4*)(b1 + d0 + 4);
        s[0]=c0.x; s[1]=c0.y; s[2]=c0.z; s[3]=c0.w; s[4]=c1.x; s[5]=c1.y; s[6]=c1.z; s[7]=c1.w;
    }
#pragma unroll
    for (int k = 0; k < 4; k++) {
        float4 w0 = *(const float4*)(w1 + k * 512 + d0);
        float4 w1v = *(const float4*)(w1 + k * 512 + d0 + 4);
        float wv[8] = {w0.x, w0.y, w0.z, w0.w, w1v.x, w1v.y, w1v.z, w1v.w};
#pragma unroll
        for (int j = 0; j < 8; j++) s[j] += av[k] * wv[j];
    }
    short8 o;
#pragma unroll
    for (int j = 0; j < 8; j++) o[j] = f2bf(fmaxf(s[j], 0.f));
    *(short8*)(h1 + (size_t)e * 512 + d0) = o;
}

// ---------------- stats finalize: stats[r] = {mu, rs} from 8 partials (4 blk x 2 wn) ----------------
__global__ void stats_finalize_kernel(const float2* __restrict__ partials,
                                      float2* __restrict__ stats, int R) {
    int r = blockIdx.x * 256 + threadIdx.x;
    if (r >= R) return;
    float s = 0.f, q = 0.f;
#pragma unroll
    for (int i = 0; i < 8; i++) {
        float2 pp = partials[(size_t)r * 8 + i];
        s += pp.x; q += pp.y;
    }
    float mu = s * (1.f / 512.f);
    float var = q * (1.f / 512.f) - mu * mu;
    stats[r] = make_float2(mu, rsqrtf(var + LN_EPS));
}

// ============ gemm256: BM=256, BN=128, BK=64, 512 thr / 8 waves ============
// Single-buffer 48 KB LDS, STAGE->sync->MFMA->sync loop (R5/R10-proven).
// EPI: 1 +bias | 4 LN-fold + gather + relu.  STATS: per-row {sum,sumsq} partials.
template <int EPI, int STATS>
__global__ __launch_bounds__(512, 4) void gemm256_kernel(
    const bf16* __restrict__ A, const bf16* __restrict__ BT,
    const float* __restrict__ bias, bf16* __restrict__ C, int M, int N, int K,
    const bf16* __restrict__ gridp, const bf16* __restrict__ meshp,
    const int* __restrict__ send, const int* __restrict__ recv,
    const float2* __restrict__ stats, const float* __restrict__ uvec,
    const float* __restrict__ vvec, float2* __restrict__ partials) {
    __shared__ short SMEM[384 * 64];   // 48 KB
    const int t = threadIdx.x;
    const int lane = t & 63, w = t >> 6;
    const int wm = w >> 1, wn = w & 1;
    const int lr = lane & 15, lh = lane >> 4;

    int gx = gridDim.x;
    int nwg = gx * gridDim.y;
    int orig = blockIdx.y * gx + blockIdx.x;
    int q = nwg >> 3, r = nwg & 7;
    int xcd = orig & 7, loc = orig >> 3;
    int wg = (xcd < r ? xcd * (q + 1) : r * (q + 1) + (xcd - r) * q) + loc;
    int bx = wg % gx, by = wg / gx;
    const int row0 = by * 256;
    const int col0 = bx * 128;

    const int sr3 = lane >> 3;
    const int su = (lane & 7) ^ sr3;
    const int scol = su * 8;
    const bf16* gp6[6];
#pragma unroll
    for (int i = 0; i < 6; i++) {
        int rr = w * 48 + i * 8 + sr3;
        if (rr < 256) {
            int ra = row0 + rr; if (ra >= M) ra = M - 1;
            gp6[i] = A + (size_t)ra * K + scol;
        } else {
            int rb = col0 + (rr - 256); if (rb >= N) rb = N - 1;
            gp6[i] = BT + (size_t)rb * K + scol;
        }
    }

    f32x4 acc[4][4];
#pragma unroll
    for (int i = 0; i < 4; i++)
#pragma unroll
        for (int j = 0; j < 4; j++) acc[i][j] = {0.f, 0.f, 0.f, 0.f};

    for (int k0 = 0; k0 < K; k0 += 64) {
#pragma unroll
        for (int i = 0; i < 6; i++)
            gload16(gp6[i] + k0, SMEM + (w * 48 + i * 8) * 64);
        __syncthreads();
#pragma unroll
        for (int kk = 0; kk < 64; kk += 32) {
            short8 af[4], bfv[4];
#pragma unroll
            for (int mf = 0; mf < 4; mf++) {
                int rowa = wm * 64 + mf * 16 + lr;
                int ua = ((kk >> 3) + lh) ^ (rowa & 7);
                af[mf] = *(const short8*)&SMEM[rowa * 64 + ua * 8];
            }
#pragma unroll
            for (int nf = 0; nf < 4; nf++) {
                int rowb = 256 + wn * 64 + nf * 16 + lr;
                int ub = ((kk >> 3) + lh) ^ (rowb & 7);
                bfv[nf] = *(const short8*)&SMEM[rowb * 64 + ub * 8];
            }
#pragma unroll
            for (int mf = 0; mf < 4; mf++)
#pragma unroll
                for (int nf = 0; nf < 4; nf++)
                    acc[mf][nf] = __builtin_amdgcn_mfma_f32_16x16x32_bf16(
                        af[mf], bfv[nf], acc[mf][nf], 0, 0, 0);
        }
        __syncthreads();
    }

    short* Cw = SMEM + w * (32 * 66);
    const int rgrp = lane >> 3, u = lane & 7;
#pragma unroll
    for (int hp = 0; hp < 2; hp++) {
#pragma unroll
        for (int mf2 = 0; mf2 < 2; mf2++) {
            int mf = hp * 2 + mf2;
#pragma unroll
            for (int nf = 0; nf < 4; nf++)
#pragma unroll
                for (int r2 = 0; r2 < 4; r2++) {
                    int rl = mf2 * 16 + lh * 4 + r2;
                    Cw[rl * 66 + nf * 16 + lr] = f2bf(acc[mf][nf][r2]);
                }
        }
#pragma unroll
        for (int rr = 0; rr < 4; rr++) {
            int rl = rr * 8 + rgrp;
            int grow = row0 + wm * 64 + hp * 32 + rl;
            int gcol = col0 + wn * 64 + u * 8;
            short8 vv = *(const short8*)&Cw[rl * 66 + u * 8];
            float vf[8];
#pragma unroll
            for (int j = 0; j < 8; j++) vf[j] = bf2f(vv[j]);
            if (EPI == 4) {
                int e = grow < M ? grow : M - 1;
                float2 st = stats[e];
                float rs = st.y, mrs = st.x * st.y;
                float4 u0 = *(const float4*)(uvec + gcol), u1 = *(const float4*)(uvec + gcol + 4);
                float4 v0 = *(const float4*)(vvec + gcol), v1 = *(const float4*)(vvec + gcol + 4);
                float uu[8] = {u0.x, u0.y, u0.z, u0.w, u1.x, u1.y, u1.z, u1.w};
                float vvv[8] = {v0.x, v0.y, v0.z, v0.w, v1.x, v1.y, v1.z, v1.w};
#pragma unroll
                for (int j = 0; j < 8; j++) vf[j] = rs * vf[j] - mrs * uu[j] + vvv[j];
            }
            {
                float4 c0 = *(const float4*)(bias + gcol);
                float4 c1 = *(const float4*)(bias + gcol + 4);
                float bb[8] = {c0.x, c0.y, c0.z, c0.w, c1.x, c1.y, c1.z, c1.w};
#pragma unroll
                for (int j = 0; j < 8; j++) vf[j] += bb[j];
            }
            if (EPI == 4) {
                int e = grow < M ? grow : M - 1;
                int rn = recv[e], sn = send[e];
                short8 gp = *(const short8*)(gridp + (size_t)rn * 512 + gcol);
                short8 mp = *(const short8*)(meshp + (size_t)sn * 512 + gcol);
#pragma unroll
                for (int j = 0; j < 8; j++) vf[j] += bf2f(gp[j]) + bf2f(mp[j]);
#pragma unroll
                for (int j = 0; j < 8; j++) vf[j] = fmaxf(vf[j], 0.f);
            }
            if (STATS) {
                float s1 = 0.f, s2 = 0.f;
#pragma unroll
                for (int j = 0; j < 8; j++) { s1 += vf[j]; s2 += vf[j] * vf[j]; }
                s1 += __shfl_xor(s1, 1, 64); s2 += __shfl_xor(s2, 1, 64);
                s1 += __shfl_xor(s1, 2, 64); s2 += __shfl_xor(s2, 2, 64);
                s1 += __shfl_xor(s1, 4, 64); s2 += __shfl_xor(s2, 4, 64);
                if (u == 0 && grow < M)
                    partials[(size_t)grow * 8 + bx * 2 + wn] = make_float2(s1, s2);
            }
            short8 o;
#pragma unroll
            for (int j = 0; j < 8; j++) o[j] = f2bf(vf[j]);
            if (grow < M && gcol < N)
                *(short8*)(C + (size_t)grow * N + gcol) = o;
        }
    }
}

// ============ gemm_bt: 128x128, R5 single-buffer loop ============
// EPI: 0 none | 1 +bias | 2 +bias+relu | 5 final-LN (N==128, f32 out)
template <int EPI>
__global__ __launch_bounds__(256, 4) void gemm_bt_kernel(
    const bf16* __restrict__ A, const bf16* __restrict__ BT,
    const float* __restrict__ bias, bf16* __restrict__ C, int M, int N, int K,
    const float* __restrict__ fg, const float* __restrict__ fb,
    float* __restrict__ OutF) {
    __shared__ short SMEM[132 * 128 + 64];
    const int t = threadIdx.x;
    const int lane = t & 63, w = t >> 6;
    const int wm = w >> 1, wn = w & 1;
    const int lr = lane & 15, lh = lane >> 4;

    int gx = gridDim.x;
    int nwg = gx * gridDim.y;
    int orig = blockIdx.y * gx + blockIdx.x;
    int q = nwg >> 3, r = nwg & 7;
    int xcd = orig & 7, loc = orig >> 3;
    int wg = (xcd < r ? xcd * (q + 1) : r * (q + 1) + (xcd - r) * q) + loc;
    int bx = wg % gx, by = wg / gx;
    const int row0 = by * 128;
    const int col0 = bx * 128;

    const int sr3 = lane >> 3;
    const int su = (lane & 7) ^ sr3;
    const int srow = w * 32 + sr3;
    const int scol = su * 8;
    const bf16* gaP[4];
    const bf16* gbP[4];
#pragma unroll
    for (int i = 0; i < 4; i++) {
        int ra = row0 + srow + i * 8; if (ra >= M) ra = M - 1;
        int rb = col0 + srow + i * 8; if (rb >= N) rb = N - 1;
        gaP[i] = A + (size_t)ra * K + scol;
        gbP[i] = BT + (size_t)rb * K + scol;
    }

    f32x4 acc[4][4];
#pragma unroll
    for (int i = 0; i < 4; i++)
#pragma unroll
        for (int j = 0; j < 4; j++) acc[i][j] = {0.f, 0.f, 0.f, 0.f};

    for (int k0 = 0; k0 < K; k0 += 64) {
        short* la = SMEM + w * 32 * 64;
        short* lb = la + 8192;
#pragma unroll
        for (int i = 0; i < 4; i++) {
            gload16(gaP[i] + k0, la + i * 8 * 64);
            gload16(gbP[i] + k0, lb + i * 8 * 64);
        }
        __syncthreads();
#pragma unroll
        for (int kk = 0; kk < 64; kk += 32) {
            short8 af[4], bfv[4];
#pragma unroll
            for (int mf = 0; mf < 4; mf++) {
                int rowa = wm * 64 + mf * 16 + lr;
                int ua = ((kk >> 3) + lh) ^ (rowa & 7);
                af[mf] = *(const short8*)&SMEM[rowa * 64 + ua * 8];
            }
#pragma unroll
            for (int nf = 0; nf < 4; nf++) {
                int rowb = wn * 64 + nf * 16 + lr;
                int ub = ((kk >> 3) + lh) ^ (rowb & 7);
                bfv[nf] = *(const short8*)&SMEM[8192 + rowb * 64 + ub * 8];
            }
#pragma unroll
            for (int mf = 0; mf < 4; mf++)
#pragma unroll
                for (int nf = 0; nf < 4; nf++)
                    acc[mf][nf] = __builtin_amdgcn_mfma_f32_16x16x32_bf16(
                        af[mf], bfv[nf], acc[mf][nf], 0, 0, 0);
        }
        __syncthreads();
    }

    if (EPI == 5) {
        short* Cs = SMEM;   // [128][132]
#pragma unroll
        for (int nf = 0; nf < 4; nf++) {
            float bv = bias[wn * 64 + nf * 16 + lr];
#pragma unroll
            for (int mf = 0; mf < 4; mf++)
#pragma unroll
                for (int r2 = 0; r2 < 4; r2++) {
                    int rl = wm * 64 + mf * 16 + lh * 4 + r2;
                    Cs[rl * 132 + wn * 64 + nf * 16 + lr] = f2bf(acc[mf][nf][r2] + bv);
                }
        }
        __syncthreads();
        int rl = w * 32 + (lane >> 1);
        int half = lane & 1;
        short8 vs[8];
        float s = 0.f, s2 = 0.f;
#pragma unroll
        for (int j8 = 0; j8 < 8; j8++) {
            vs[j8] = *(const short8*)&Cs[rl * 132 + half * 64 + j8 * 8];
#pragma unroll
            for (int j = 0; j < 8; j++) {
                float f = bf2f(vs[j8][j]);
                s += f; s2 += f * f;
            }
        }
        s += __shfl_xor(s, 1, 64);
        s2 += __shfl_xor(s2, 1, 64);
        float mu = s * (1.f / 128.f);
        float var = s2 * (1.f / 128.f) - mu * mu;
        float rs = rsqrtf(var + LN_EPS);
        int grow = row0 + rl;
#pragma unroll
        for (int j8 = 0; j8 < 8; j8++) {
            int c0 = half * 64 + j8 * 8;
            float4 g0 = *(const float4*)(fg + c0), g1 = *(const float4*)(fg + c0 + 4);
            float4 b0 = *(const float4*)(fb + c0), b1v = *(const float4*)(fb + c0 + 4);
            float gg[8] = {g0.x, g0.y, g0.z, g0.w, g1.x, g1.y, g1.z, g1.w};
            float bb[8] = {b0.x, b0.y, b0.z, b0.w, b1v.x, b1v.y, b1v.z, b1v.w};
            float4 o0, o1;
#pragma unroll
            for (int j = 0; j < 8; j++) {
                float y = (bf2f(vs[j8][j]) - mu) * rs * gg[j] + bb[j];
                if (j < 4) ((float*)&o0)[j] = y; else ((float*)&o1)[j - 4] = y;
            }
            *(float4*)(OutF + (size_t)grow * 128 + c0) = o0;
            *(float4*)(OutF + (size_t)grow * 128 + c0 + 4) = o1;
        }
        return;
    }

    short* Cw = SMEM + w * (32 * 66);
    const int rgrp = lane >> 3, u = lane & 7;
#pragma unroll
    for (int hp = 0; hp < 2; hp++) {
#pragma unroll
        for (int mf2 = 0; mf2 < 2; mf2++) {
            int mf = hp * 2 + mf2;
#pragma unroll
            for (int nf = 0; nf < 4; nf++)
#pragma unroll
                for (int r2 = 0; r2 < 4; r2++) {
                    int rl = mf2 * 16 + lh * 4 + r2;
                    Cw[rl * 66 + nf * 16 + lr] = f2bf(acc[mf][nf][r2]);
                }
        }
#pragma unroll
        for (int rr = 0; rr < 4; rr++) {
            int rl = rr * 8 + rgrp;
            int grow = row0 + wm * 64 + hp * 32 + rl;
            int gcol = col0 + wn * 64 + u * 8;
            short8 vv = *(const short8*)&Cw[rl * 66 + u * 8];
            float vf[8];
#pragma unroll
            for (int j = 0; j < 8; j++) vf[j] = bf2f(vv[j]);
            if (EPI >= 1) {
                float4 c0 = *(const float4*)(bias + gcol);
                float4 c1 = *(const float4*)(bias + gcol + 4);
                float bb[8] = {c0.x, c0.y, c0.z, c0.w, c1.x, c1.y, c1.z, c1.w};
#pragma unroll
                for (int j = 0; j < 8; j++) vf[j] += bb[j];
            }
            if (EPI == 2) {
#pragma unroll
                for (int j = 0; j < 8; j++) vf[j] = fmaxf(vf[j], 0.f);
            }
            short8 o;
#pragma unroll
            for (int j = 0; j < 8; j++) o[j] = f2bf(vf[j]);
            if (grow < M && gcol < N)
                *(short8*)(C + (size_t)grow * N + gcol) = o;
        }
    }
}

// ---------------- LayerNorm with residual add (DN=512) ----------------
__global__ void ln_resid_kernel(const bf16* __restrict__ X, const float* __restrict__ gw,
                                const float* __restrict__ bw, bf16* __restrict__ outb,
                                const bf16* __restrict__ resid, int R) {
    int row = blockIdx.x * 4 + (threadIdx.x >> 6);
    if (row >= R) return;
    int lane = threadIdx.x & 63;
    short8 t8 = *(const short8*)(X + (size_t)row * 512 + lane * 8);
    float v[8];
#pragma unroll
    for (int j = 0; j < 8; j++) v[j] = bf2f(t8[j]);
    float s = 0.f, s2 = 0.f;
#pragma unroll
    for (int j = 0; j < 8; j++) { s += v[j]; s2 += v[j] * v[j]; }
#pragma unroll
    for (int o = 32; o > 0; o >>= 1) {
        s += __shfl_xor(s, o, 64);
        s2 += __shfl_xor(s2, o, 64);
    }
    float mu = s * (1.f / 512.f);
    float var = s2 * (1.f / 512.f) - mu * mu;
    float rs = rsqrtf(var + LN_EPS);
    int d0 = lane * 8;
    short8 rv = *(const short8*)(resid + (size_t)row * 512 + d0);
    short8 o;
#pragma unroll
    for (int j = 0; j < 8; j++) {
        float y = (v[j] - mu) * rs * gw[d0 + j] + bw[d0 + j];
        o[j] = f2bf(bf2f(rv[j]) + y);
    }
    *(short8*)(outb + (size_t)row * 512 + d0) = o;
}

// ---------------- CSR build ----------------
__global__ void degree_kernel(const int* __restrict__ recv, int* __restrict__ deg, int E) {
    int e = blockIdx.x * 256 + threadIdx.x;
    if (e < E) atomicAdd(&deg[recv[e]], 1);
}

__global__ void scan_kernel(const int* __restrict__ deg, int* __restrict__ off) {
    __shared__ int partial[1024];
    int t = threadIdx.x;
    int base = t * 16;
    int v[16];
    int s = 0;
#pragma unroll
    for (int i = 0; i < 16; i++) { v[i] = deg[base + i]; s += v[i]; }
    partial[t] = s;
    __syncthreads();
    for (int o = 1; o < 1024; o <<= 1) {
        int x = (t >= o) ? partial[t - o] : 0;
        __syncthreads();
        partial[t] += x;
        __syncthreads();
    }
    int run = (t == 0) ? 0 : partial[t - 1];
#pragma unroll
    for (int i = 0; i < 16; i++) { off[base + i] = run; run += v[i]; }
    if (t == 1023) off[16384] = run;
}

__global__ void scatter_kernel(const int* __restrict__ recv, const int* __restrict__ off,
                               int* __restrict__ cnt, int* __restrict__ edges, int E) {
    int e = blockIdx.x * 256 + threadIdx.x;
    if (e < E) {
        int r = recv[e];
        int p = atomicAdd(&cnt[r], 1);
        edges[off[r] + p] = e;
    }
}

// ---------------- aggregate LN(msg) by receiver + build X2 = cat(grid_bf, aggr) ----------------
__global__ void aggregate_kernel(const bf16* __restrict__ T5, const float2* __restrict__ stats,
                                 const float* __restrict__ gw, const float* __restrict__ bw,
                                 const bf16* __restrict__ gridb,
                                 const int* __restrict__ off, const int* __restrict__ edges,
                                 bf16* __restrict__ X2, int G) {
    int g = blockIdx.x * 4 + (threadIdx.x >> 6);
    if (g >= G) return;
    int lane = threadIdx.x & 63;
    int d0 = lane * 8;
    float gg[8], bb[8];
    {
        float4 a = *(const float4*)(gw + d0), b = *(const float4*)(gw + d0 + 4);
        gg[0]=a.x; gg[1]=a.y; gg[2]=a.z; gg[3]=a.w; gg[4]=b.x; gg[5]=b.y; gg[6]=b.z; gg[7]=b.w;
        float4 c = *(const float4*)(bw + d0), d = *(const float4*)(bw + d0 + 4);
        bb[0]=c.x; bb[1]=c.y; bb[2]=c.z; bb[3]=c.w; bb[4]=d.x; bb[5]=d.y; bb[6]=d.z; bb[7]=d.w;
    }
    float s[8] = {0.f, 0.f, 0.f, 0.f, 0.f, 0.f, 0.f, 0.f};
    int a = off[g], b = off[g + 1];
    for (int i = a; i < b; i++) {
        int e = edges[i];
        float2 st = stats[e];
        short8 m = *(const short8*)(T5 + (size_t)e * 512 + d0);
#pragma unroll
        for (int j = 0; j < 8; j++)
            s[j] += (bf2f(m[j]) - st.x) * st.y * gg[j] + bb[j];
    }
    *(short8*)(X2 + (size_t)g * 1024 + d0) = *(const short8*)(gridb + (size_t)g * 512 + d0);
    short8 o;
#pragma unroll
    for (int j = 0; j < 8; j++) o[j] = f2bf(s[j]);
    *(short8*)(X2 + (size_t)g * 1024 + 512 + d0) = o;
}

extern "C" void kernel_launch(void* const* d_in, const int* in_sizes, int n_in,
                              void* d_out, int out_size, void* d_ws, size_t ws_size,
                              hipStream_t stream) {
    const int NM = 2562, NG = 16384, NE = 49152;
    const float* mesh   = (const float*)d_in[0];
    const float* grid   = (const float*)d_in[1];
    const float* attr   = (const float*)d_in[2];
    const int*   eidx   = (const int*)d_in[3];
    const int*   send   = eidx;
    const int*   recv   = eidx + NE;
    const float* emlp_w1 = (const float*)d_in[4];
    const float* emlp_b1 = (const float*)d_in[5];
    const float* emlp_w2 = (const float*)d_in[6];
    const float* emlp_b2 = (const float*)d_in[7];
    const float* emlp_g  = (const float*)d_in[8];
    const float* emlp_be = (const float*)d_in[9];
    const float* ge_w1 = (const float*)d_in[10];
    const float* ge_b1 = (const float*)d_in[11];
    const float* ge_w2 = (const float*)d_in[12];
    const float* ge_b2 = (const float*)d_in[13];
    const float* ge_g  = (const float*)d_in[14];
    const float* ge_be = (const float*)d_in[15];
    const float* gn_w1 = (const float*)d_in[16];
    const float* gn_b1 = (const float*)d_in[17];
    const float* gn_w2 = (const float*)d_in[18];
    const float* gn_b2 = (const float*)d_in[19];
    const float* gn_g  = (const float*)d_in[20];
    const float* gn_be = (const float*)d_in[21];
    const float* fin_w1 = (const float*)d_in[22];
    const float* fin_b1 = (const float*)d_in[23];
    const float* fin_w2 = (const float*)d_in[24];
    const float* fin_b2 = (const float*)d_in[25];
    const float* fin_g  = (const float*)d_in[26];
    const float* fin_be = (const float*)d_in[27];

    char* p = (char*)d_ws;
    auto take = [&](size_t bytes) -> char* {
        char* r = p;
        p += (bytes + 255) & ~(size_t)255;
        return r;
    };
    bf16* emlp_w2T = (bf16*)take((size_t)512 * 512 * 2);
    bf16* geA_T    = (bf16*)take((size_t)512 * 512 * 2);
    bf16* geB_T    = (bf16*)take((size_t)512 * 512 * 2);
    bf16* geC_T    = (bf16*)take((size_t)512 * 512 * 2);   // pre-scaled by emlp_g
    bf16* ge_w2T   = (bf16*)take((size_t)512 * 512 * 2);
    bf16* gn_w1T   = (bf16*)take((size_t)512 * 1024 * 2);
    bf16* gn_w2T   = (bf16*)take((size_t)512 * 512 * 2);
    bf16* fin_w1T  = (bf16*)take((size_t)512 * 512 * 2);
    bf16* fin_w2T  = (bf16*)take((size_t)128 * 512 * 2);
    bf16* grid_bf  = (bf16*)take((size_t)NG * 512 * 2);
    bf16* mesh_bf  = (bf16*)take((size_t)NM * 512 * 2);
    bf16* bufA     = (bf16*)take((size_t)NE * 512 * 2);
    bf16* bufB     = (bf16*)take((size_t)NE * 512 * 2);
    bf16* bufC     = (bf16*)take((size_t)NG * 512 * 2);
    bf16* bufD     = (bf16*)take((size_t)NM * 512 * 2);
    float2* stats  = (float2*)take((size_t)NE * 8);
    float2* parts  = (float2*)take((size_t)NE * 8 * 8);
    float* uvecW   = (float*)take((size_t)512 * 4);
    float* vvecW   = (float*)take((size_t)512 * 4);
    int*  deg      = (int*)take((size_t)NG * 4);
    int*  cnt      = (int*)take((size_t)NG * 4);
    int*  csr_off  = (int*)take((size_t)(NG + 1) * 4);
    int*  csr_edge = (int*)take((size_t)NE * 4);

    const bf16* nbf = nullptr; const int* ni = nullptr;
    const float2* nst = nullptr; const float* nf = nullptr;
    float2* nfp = nullptr;

    // 1) transpose + bf16-convert all GEMM weights (geC pre-scaled by emlp_g)
    TDescs td;
    td.d[0] = {emlp_w2, emlp_w2T, 512, 512, 0, nullptr};
    td.d[1] = {ge_w1,   geA_T,    512, 512, 0, nullptr};
    td.d[2] = {ge_w1,   geB_T,    512, 512, 512, nullptr};
    td.d[3] = {ge_w1,   geC_T,    512, 512, 1024, emlp_g};
    td.d[4] = {ge_w2,   ge_w2T,   512, 512, 0, nullptr};
    td.d[5] = {gn_w1,   gn_w1T,  1024, 512, 0, nullptr};
    td.d[6] = {gn_w2,   gn_w2T,   512, 512, 0, nullptr};
    td.d[7] = {fin_w1,  fin_w1T,  512, 512, 0, nullptr};
    td.d[8] = {fin_w2,  fin_w2T,  512, 128, 0, nullptr};
    hipLaunchKernelGGL(transpose_all_kernel, dim3(32, 16, 9), dim3(256), 0, stream, td);
    hipLaunchKernelGGL(uv_kernel, dim3(2), dim3(256), 0, stream,
                       ge_w1, emlp_g, emlp_be, uvecW, vvecW);

    // 2) bf16 inputs + CSR build
    hipLaunchKernelGGL(cvt_bf16_kernel, dim3((NG * 512 / 4 + 255) / 256), dim3(256), 0, stream,
                       grid, grid_bf, NG * 512);
    hipLaunchKernelGGL(cvt_bf16_kernel, dim3((NM * 512 / 4 + 255) / 256), dim3(256), 0, stream,
                       mesh, mesh_bf, NM * 512);
    hipMemsetAsync(deg, 0, (size_t)NG * 4, stream);
    hipMemsetAsync(cnt, 0, (size_t)NG * 4, stream);
    hipLaunchKernelGGL(degree_kernel, dim3((NE + 255) / 256), dim3(256), 0, stream, recv, deg, NE);
    hipLaunchKernelGGL(scan_kernel, dim3(1), dim3(1024), 0, stream, deg, csr_off);
    hipLaunchKernelGGL(scatter_kernel, dim3((NE + 255) / 256), dim3(256), 0, stream,
                       recv, csr_off, cnt, csr_edge, NE);

    // 3) H1 = relu(attr @ emlp_w1 + b1) -> bufA
    hipLaunchKernelGGL(edge_l1_kernel, dim3(NE / 4), dim3(256), 0, stream,
                       attr, emlp_w1, emlp_b1, bufA, NE);
    // 4) T2 = H1 @ emlp_w2 + b2 -> bufB, with fused LN stats partials
    hipLaunchKernelGGL((gemm256_kernel<1, 1>), dim3(4, NE / 256), dim3(512), 0, stream,
                       bufA, emlp_w2T, emlp_b2, bufB, NE, 512, 512,
                       nbf, nbf, ni, ni, nst, nf, nf, parts);
    // 5) finalize T2 stats
    hipLaunchKernelGGL(stats_finalize_kernel, dim3((NE + 255) / 256), dim3(256), 0, stream,
                       parts, stats, NE);

    // 6) grid_proj -> bufC
    hipLaunchKernelGGL(gemm_bt_kernel<0>, dim3(4, NG / 128), dim3(256), 0, stream,
                       grid_bf, geA_T, nf, bufC, NG, 512, 512, nf, nf, (float*)nullptr);
    // 7) mesh_proj -> bufD
    hipLaunchKernelGGL(gemm_bt_kernel<0>, dim3(4, (NM + 127) / 128), dim3(256), 0, stream,
                       mesh_bf, geB_T, nf, bufD, NM, 512, 512, nf, nf, (float*)nullptr);
    // 8) H2 = relu( LNfold(T2)@geC' + grid_proj[recv] + mesh_proj[send] + ge_b1 ) -> bufA
    hipLaunchKernelGGL((gemm256_kernel<4, 0>), dim3(4, NE / 256), dim3(512), 0, stream,
                       bufB, geC_T, ge_b1, bufA, NE, 512, 512,
                       bufC, bufD, send, recv, stats, uvecW, vvecW, nfp);
    // 9) T5 = H2 @ ge_w2 + b2 -> bufB, with fused LN stats partials
    hipLaunchKernelGGL((gemm256_kernel<1, 1>), dim3(4, NE / 256), dim3(512), 0, stream,
                       bufA, ge_w2T, ge_b2, bufB, NE, 512, 512,
                       nbf, nbf, ni, ni, nst, nf, nf, parts);
    // 10) finalize T5 stats
    hipLaunchKernelGGL(stats_finalize_kernel, dim3((NE + 255) / 256), dim3(256), 0, stream,
                       parts, stats, NE);
    // 11) X2 = cat(grid_bf, segment_sum(LN(T5))) -> bufA
    hipLaunchKernelGGL(aggregate_kernel, dim3(NG / 4), dim3(256), 0, stream,
                       bufB, stats, ge_g, ge_be, grid_bf, csr_off, csr_edge, bufA, NG);

    // 12) H3 = relu(X2 @ gn_w1 + b1) -> bufC
    hipLaunchKernelGGL(gemm_bt_kernel<2>, dim3(4, NG / 128), dim3(256), 0, stream,
                       bufA, gn_w1T, gn_b1, bufC, NG, 512, 1024, nf, nf, (float*)nullptr);
    // 13) T8 = H3 @ gn_w2 + b2 -> bufB
    hipLaunchKernelGGL(gemm_bt_kernel<1>, dim3(4, NG / 128), dim3(256), 0, stream,
                       bufC, gn_w2T, gn_b2, bufB, NG, 512, 512, nf, nf, (float*)nullptr);
    // 14) latent = grid_bf + LN(T8)*g+b -> bufA
    hipLaunchKernelGGL(ln_resid_kernel, dim3(NG / 4), dim3(256), 0, stream,
                       bufB, gn_g, gn_be, bufA, grid_bf, NG);

    // 15) H4 = relu(latent @ fin_w1 + b1) -> bufC
    hipLaunchKernelGGL(gemm_bt_kernel<2>, dim3(4, NG / 128), dim3(256), 0, stream,
                       bufA, fin_w1T, fin_b1, bufC, NG, 512, 512, nf, nf, (float*)nullptr);
    // 16) out = LN(H4 @ fin_w2 + b2)*fg+fb -> d_out (f32)
    hipLaunchKernelGGL(gemm_bt_kernel<5>, dim3(1, NG / 128), dim3(256), 0, stream,
                       bufC, fin_w2T, fin_b2, (bf16*)nullptr, NG, 128, 512,
                       fin_g, fin_be, (float*)d_out);
}